// Round 1
// baseline (7208.238 us; speedup 1.0000x reference)
//
#include <hip/hip_runtime.h>
#include <hip/hip_bf16.h>

// PK1Block: B=2 S=2048 DIM=2048 NH=16 NKV=4 HD=128 NE=8 TOPK=2 HID=SHID=1024
// External dtype: fp32 (confirmed R4). Pre-gate chain stays pure fp32 (routing
// is sensitive to ~0.003 logit noise). Post-gate MoE = expert-grouped bf16
// MFMA GEMMs (R4 evidence: per-token MoE re-read weights -> 129 GB HBM, 34 ms).
// R5: fp32 GEMM rebuilt: 128x128 tile, 8x8/thread, k-major LDS + ds_read_b128
// fragments, register prefetch. Was 64x64 scalar-LDS-read bound (~27 TF).
#define B_    2
#define S_    2048
#define DIM_  2048
#define NH_   16
#define NKV_  4
#define HD_   128
#define NE_   8
#define HID_  1024
#define T_    (B_*S_)          // 4096 tokens

typedef unsigned short u16;
typedef unsigned int   u32;

#define DT_BF16 1
#define DT_F32  2

template<typename T> struct dtid;
template<> struct dtid<float> { static constexpr int v = DT_F32;  };
template<> struct dtid<u16>   { static constexpr int v = DT_BF16; };

typedef __attribute__((ext_vector_type(8))) short short8;   // 8 x bf16
typedef __attribute__((ext_vector_type(4))) float f32x4;

__device__ __forceinline__ float u2f(u16 u) {
    union { u32 i; float f; } v; v.i = ((u32)u) << 16; return v.f;
}
__device__ __forceinline__ u16 f2bf(float f) {
    union { float f; u32 i; } v; v.f = f;
    u32 x = v.i;
    return (u16)((x + 0x7fffu + ((x >> 16) & 1u)) >> 16);   // RNE
}
__device__ __forceinline__ u32 pack2(float lo, float hi) {
    return (u32)f2bf(lo) | ((u32)f2bf(hi) << 16);
}

template<typename T> __device__ __forceinline__ float ldf(const T* p);
template<> __device__ __forceinline__ float ldf<float>(const float* p) { return *p; }
template<> __device__ __forceinline__ float ldf<u16>(const u16* p)     { return u2f(*p); }

template<typename T> __device__ __forceinline__ void stf(T* p, float v);
template<> __device__ __forceinline__ void stf<float>(float* p, float v) { *p = v; }
template<> __device__ __forceinline__ void stf<u16>(u16* p, float v)     { *p = f2bf(v); }

template<typename T> __device__ __forceinline__ float4 ld4(const T* p);
template<> __device__ __forceinline__ float4 ld4<float>(const float* p) {
    return *(const float4*)p;
}
template<> __device__ __forceinline__ float4 ld4<u16>(const u16* p) {
    ushort4 q = *(const ushort4*)p;
    return make_float4(u2f(q.x), u2f(q.y), u2f(q.z), u2f(q.w));
}

// ---------------------------------------------------------------- dtype detect
__global__ void detect_kernel(const u32* __restrict__ fcos_words,
                              int* __restrict__ flag)
{
    *flag = (fcos_words[0] == 0x3F800000u) ? DT_F32 : DT_BF16;
}

__global__ void init_kernel(int* __restrict__ counts)   // counts[16]+cursor[16]
{
    if (threadIdx.x < 32) counts[threadIdx.x] = 0;
}

// ------------------------------------------------- RMSNorm: IT in -> fp32 out
template<typename IT, typename WT>
__global__ __launch_bounds__(256) void rmsnorm_kernel(const int* __restrict__ flag,
                                                      const IT* __restrict__ xin,
                                                      const WT* __restrict__ w,
                                                      float* __restrict__ out)
{
    if (*flag != dtid<WT>::v) return;
    int t = blockIdx.x;
    const IT* xb = xin + (size_t)t * DIM_;
    float ss = 0.f;
    for (int d = threadIdx.x; d < DIM_; d += 256) {
        float v = ldf(xb + d);
        ss += v * v;
    }
    #pragma unroll
    for (int o = 32; o > 0; o >>= 1) ss += __shfl_xor(ss, o);
    __shared__ float red[4];
    if ((threadIdx.x & 63) == 0) red[threadIdx.x >> 6] = ss;
    __syncthreads();
    float tot = red[0] + red[1] + red[2] + red[3];
    float inv = rsqrtf(tot * (1.0f / DIM_) + 1e-6f);
    for (int d = threadIdx.x; d < DIM_; d += 256)
        out[(size_t)t * DIM_ + d] = ldf(xb + d) * inv * ldf(w + d);
}

// ---------------------- GEMM: A(fp32 ws) @ B(T) -> CF(fp32) [+resid(T)]
// 128x128 tile, 256 threads, 8x8 per thread. k-major LDS (As/Bs [16][132]),
// fragment reads are 2x ds_read_b128 each with <=2-way bank aliasing.
// Register prefetch of the next k-slab overlaps global latency with compute.
template<typename T>
__global__ __launch_bounds__(256) void gemm_kernel(const int* __restrict__ flag,
                                                   const float* __restrict__ A,
                                                   const T* __restrict__ Bw,
                                                   float* __restrict__ CF,
                                                   const T* __restrict__ resid,
                                                   int M, int N, int K)
{
    if (*flag != dtid<T>::v) return;
    __shared__ float As[16][132];
    __shared__ float Bs[16][132];
    int t  = threadIdx.x;
    int bm = blockIdx.y, bn = blockIdx.x;

    // staging mapping (coalesced 64B-granule loads)
    int ar = t >> 2;             // A row within tile: 0..63 (and +64)
    int ak = (t & 3) << 2;       // A k-offset: 0,4,8,12
    int bkr = t >> 4;            // B k-row: 0..15
    int bc  = (t & 15) << 3;     // B col-offset: 0..120

    const float* Ap0 = A + (size_t)(bm * 128 + ar) * K + ak;
    const float* Ap1 = Ap0 + (size_t)64 * K;
    const T*     Bp  = Bw + (size_t)bkr * N + bn * 128 + bc;

    // fragment mapping: 8 m-chunks x 8 n-chunks per wave (2-way bank alias max)
    int lane = t & 63, w = t >> 6;
    int mi = ((lane & 7) + ((w & 1) << 3)) << 3;   // 0..120
    int ni = ((lane >> 3) + ((w >> 1) << 3)) << 3; // 0..120

    float acc[8][8] = {};

    float4 pa0 = *(const float4*)(Ap0);
    float4 pa1 = *(const float4*)(Ap1);
    float4 pb0 = ld4(Bp);
    float4 pb1 = ld4(Bp + 4);

    for (int k0 = 0; k0 < K; k0 += 16) {
        // commit staged regs to LDS (k-major, transposed for A)
        As[ak + 0][ar]      = pa0.x; As[ak + 1][ar]      = pa0.y;
        As[ak + 2][ar]      = pa0.z; As[ak + 3][ar]      = pa0.w;
        As[ak + 0][ar + 64] = pa1.x; As[ak + 1][ar + 64] = pa1.y;
        As[ak + 2][ar + 64] = pa1.z; As[ak + 3][ar + 64] = pa1.w;
        *(float4*)&Bs[bkr][bc]     = pb0;
        *(float4*)&Bs[bkr][bc + 4] = pb1;
        __syncthreads();

        // prefetch next k-slab into registers (hidden under compute)
        if (k0 + 16 < K) {
            pa0 = *(const float4*)(Ap0 + k0 + 16);
            pa1 = *(const float4*)(Ap1 + k0 + 16);
            pb0 = ld4(Bp + (size_t)(k0 + 16) * N);
            pb1 = ld4(Bp + (size_t)(k0 + 16) * N + 4);
        }

        #pragma unroll
        for (int kk = 0; kk < 16; ++kk) {
            float4 a0 = *(const float4*)&As[kk][mi];
            float4 a1 = *(const float4*)&As[kk][mi + 4];
            float4 b0 = *(const float4*)&Bs[kk][ni];
            float4 b1 = *(const float4*)&Bs[kk][ni + 4];
            float a[8] = { a0.x, a0.y, a0.z, a0.w, a1.x, a1.y, a1.z, a1.w };
            float b[8] = { b0.x, b0.y, b0.z, b0.w, b1.x, b1.y, b1.z, b1.w };
            #pragma unroll
            for (int i = 0; i < 8; ++i)
                #pragma unroll
                for (int j = 0; j < 8; ++j) acc[i][j] += a[i] * b[j];
        }
        __syncthreads();
    }

    // epilogue
    #pragma unroll
    for (int i = 0; i < 8; ++i) {
        size_t off = (size_t)(bm * 128 + mi + i) * N + bn * 128 + ni;
        #pragma unroll
        for (int j = 0; j < 8; ++j) {
            float c = acc[i][j];
            if (resid) c += ldf(resid + off + j);
            CF[off + j] = c;
        }
    }
}

// ---------------------------------------------------------------- RoPE (fp32, in place)
template<typename FT>
__global__ __launch_bounds__(256) void rope_kernel(const int* __restrict__ flag,
                                                   float* __restrict__ t,
                                                   const FT* __restrict__ fc,
                                                   const FT* __restrict__ fs,
                                                   int nheads, int npairs)
{
    if (*flag != dtid<FT>::v) return;
    int gid = blockIdx.x * 256 + threadIdx.x;
    if (gid >= npairs) return;
    int i    = gid & 63;
    int rest = gid >> 6;
    int h    = rest % nheads;
    int tok  = rest / nheads;
    int spos = tok & (S_ - 1);
    float c = ldf(fc + spos * 64 + i);
    float s = ldf(fs + spos * 64 + i);
    size_t base = ((size_t)tok * nheads + h) * HD_ + 2 * i;
    float t1 = t[base], t2 = t[base + 1];
    t[base]     = t1 * c - t2 * s;
    t[base + 1] = t1 * s + t2 * c;
}

// ---------------------------------------------------------------- fp32 -> bf16 cast
__global__ __launch_bounds__(256) void cast_kernel(const int* __restrict__ flag,
                                                   const float* __restrict__ src,
                                                   u16* __restrict__ dst, int n)
{
    if (*flag != DT_BF16) return;
    int i = blockIdx.x * 256 + threadIdx.x;
    if (i < n) dst[i] = f2bf(src[i]);
}

// --------------------------------------------- Flash causal attention (fp32)
__global__ __launch_bounds__(64) void attn_kernel(const int* __restrict__ flag,
                                                  int want,
                                                  float* __restrict__ q,
                                                  const float* __restrict__ k,
                                                  const float* __restrict__ v)
{
    if (*flag != want) return;
    int gid  = blockIdx.x;
    int qpos = gid & (S_ - 1);
    int bh   = gid >> 11;
    int h    = bh & (NH_ - 1);
    int b    = bh >> 4;
    int kvh  = h >> 2;
    int lane = threadIdx.x;

    size_t qoff = ((size_t)(b * S_ + qpos) * NH_ + h) * HD_;
    float q0 = q[qoff + lane], q1 = q[qoff + lane + 64];
    const float* kb = k + (size_t)b * S_ * NKV_ * HD_ + kvh * HD_;
    const float* vb = v + (size_t)b * S_ * NKV_ * HD_ + kvh * HD_;

    float m = -1e30f, l = 0.f, o0 = 0.f, o1 = 0.f;
    const float scale = 0.08838834764831845f;

    for (int j = 0; j <= qpos; ++j) {
        const float* kr = kb + (size_t)j * (NKV_ * HD_);
        float s = q0 * kr[lane] + q1 * kr[lane + 64];
        #pragma unroll
        for (int off = 32; off > 0; off >>= 1) s += __shfl_xor(s, off);
        s *= scale;
        float mn    = fmaxf(m, s);
        float alpha = __expf(m - mn);
        float p     = __expf(s - mn);
        const float* vr = vb + (size_t)j * (NKV_ * HD_);
        l  = l  * alpha + p;
        o0 = o0 * alpha + p * vr[lane];
        o1 = o1 * alpha + p * vr[lane + 64];
        m = mn;
    }
    float invl = 1.f / l;
    q[qoff + lane]      = o0 * invl;
    q[qoff + lane + 64] = o1 * invl;
}

// ---------------------------------------------------------------- top-2 gate
template<typename T>
__global__ __launch_bounds__(64) void gate_kernel(const int* __restrict__ flag,
                                                  const float* __restrict__ xt,
                                                  const T* __restrict__ gw,
                                                  int* __restrict__ eidx,
                                                  float* __restrict__ egw,
                                                  int* __restrict__ counts)
{
    if (*flag != dtid<T>::v) return;
    int t = blockIdx.x, lane = threadIdx.x;
    float acc[NE_] = {};
    const float* xr = xt + (size_t)t * DIM_;
    for (int d = lane; d < DIM_; d += 64) {
        float xd = xr[d];
        #pragma unroll
        for (int e = 0; e < NE_; ++e) acc[e] += xd * ldf(gw + d * NE_ + e);
    }
    #pragma unroll
    for (int e = 0; e < NE_; ++e)
        #pragma unroll
        for (int off = 32; off > 0; off >>= 1) acc[e] += __shfl_xor(acc[e], off);
    if (lane == 0) {
        int i0 = 0; float m0 = acc[0];
        #pragma unroll
        for (int e = 1; e < NE_; ++e) if (acc[e] > m0) { m0 = acc[e]; i0 = e; }
        int i1 = (i0 == 0) ? 1 : 0; float m1 = acc[i1];
        for (int e = i1 + 1; e < NE_; ++e)
            if (e != i0 && acc[e] > m1) { m1 = acc[e]; i1 = e; }
        float e1  = __expf(m1 - m0);
        float inv = 1.f / (1.f + e1);
        eidx[t * 2] = i0; eidx[t * 2 + 1] = i1;
        egw [t * 2] = inv; egw [t * 2 + 1] = e1 * inv;
        atomicAdd(&counts[i0], 1);
        atomicAdd(&counts[i1], 1);
    }
}

__global__ void offs_kernel(const int* __restrict__ counts, int* __restrict__ offs)
{
    if (threadIdx.x == 0) {
        int off = 0;
        for (int e = 0; e < NE_; ++e) { offs[e] = off; off += counts[e]; }
    }
}

__global__ __launch_bounds__(256) void scatter_kernel(const int* __restrict__ eidx,
                                                      const int* __restrict__ offs,
                                                      int* __restrict__ cursor,
                                                      int* __restrict__ list)
{
    int s = blockIdx.x * 256 + threadIdx.x;
    if (s >= T_ * 2) return;
    int e = eidx[s] & 7;
    int pos = atomicAdd(&cursor[e], 1);
    list[offs[e] + pos] = s;
}

// ------------------- MoE phase A: he = silu(X@W1) * (X@W3), bf16 MFMA
// grid (HID/128, 128, 9). e==8 -> shared expert over all tokens.
__global__ __launch_bounds__(256) void moe_h_kernel(const int* __restrict__ flag,
                                                    const float* __restrict__ h2,
                                                    const float* __restrict__ w1,
                                                    const float* __restrict__ w3,
                                                    const float* __restrict__ sw1,
                                                    const float* __restrict__ sw3,
                                                    const int* __restrict__ list,
                                                    const int* __restrict__ counts,
                                                    const int* __restrict__ offs,
                                                    u16* __restrict__ he)
{
    if (*flag != DT_F32) return;
    int e   = blockIdx.z;
    int cnt = (e < 8) ? counts[e] : T_;
    int my0 = blockIdx.y * 64;
    if (my0 >= cnt) return;
    int n0   = blockIdx.x * 128;
    int base = ((e < 8) ? offs[e] : 2 * T_) + my0;   // he entry base
    const float* W1 = (e < 8) ? w1 + (size_t)e * DIM_ * HID_ : sw1;
    const float* W3 = (e < 8) ? w3 + (size_t)e * DIM_ * HID_ : sw3;

    __shared__ int toks[64];
    __shared__ u16 Bs[2][128 * 40];   // [n][k] bf16, pitch 40 (16B-aligned rows)

    int t = threadIdx.x;
    if (t < 64) {
        int m  = my0 + t;
        int mm = m < cnt ? m : cnt - 1;
        toks[t] = (e < 8) ? (list[((e < 8) ? offs[e] : 0) + mm] >> 1) : mm;
    }
    __syncthreads();

    int wave = t >> 6, lane = t & 63;
    int q = lane >> 4, l16 = lane & 15;
    int mytok = toks[wave * 16 + l16];          // A-row token for this lane
    const float* arow = h2 + (size_t)mytok * DIM_;

    int kp = t & 15;        // k-pair 0..15  (k = 2*kp, 2*kp+1)
    int ng = t >> 4;        // n-group 0..15 (n = 8*ng .. +8)

    f32x4 acc[2][8];
    #pragma unroll
    for (int m_ = 0; m_ < 2; ++m_)
        #pragma unroll
        for (int nt = 0; nt < 8; ++nt) acc[m_][nt] = (f32x4){0.f, 0.f, 0.f, 0.f};

    for (int d0 = 0; d0 < DIM_; d0 += 32) {
        __syncthreads();
        // stage W1, W3 tiles transposed into Bs[n][k]
        #pragma unroll
        for (int mat = 0; mat < 2; ++mat) {
            const float* W = (mat ? W3 : W1) + (size_t)(d0 + 2 * kp) * HID_ + n0 + 8 * ng;
            float4 a0 = *(const float4*)(W);
            float4 a1 = *(const float4*)(W + 4);
            float4 b0 = *(const float4*)(W + HID_);
            float4 b1 = *(const float4*)(W + HID_ + 4);
            u32* dst = (u32*)Bs[mat] + kp;
            dst[(8 * ng + 0) * 20] = pack2(a0.x, b0.x);
            dst[(8 * ng + 1) * 20] = pack2(a0.y, b0.y);
            dst[(8 * ng + 2) * 20] = pack2(a0.z, b0.z);
            dst[(8 * ng + 3) * 20] = pack2(a0.w, b0.w);
            dst[(8 * ng + 4) * 20] = pack2(a1.x, b1.x);
            dst[(8 * ng + 5) * 20] = pack2(a1.y, b1.y);
            dst[(8 * ng + 6) * 20] = pack2(a1.z, b1.z);
            dst[(8 * ng + 7) * 20] = pack2(a1.w, b1.w);
        }
        __syncthreads();
        // A fragment direct from global (fp32 -> bf16)
        const float* ap = arow + d0 + q * 8;
        float4 af0 = *(const float4*)(ap);
        float4 af1 = *(const float4*)(ap + 4);
        short8 afr;
        afr[0] = (short)f2bf(af0.x); afr[1] = (short)f2bf(af0.y);
        afr[2] = (short)f2bf(af0.z); afr[3] = (short)f2bf(af0.w);
        afr[4] = (short)f2bf(af1.x); afr[5] = (short)f2bf(af1.y);
        afr[6] = (short)f2bf(af1.z); afr[7] = (short)f2bf(af1.w);
        #pragma unroll
        for (int nt = 0; nt < 8; ++nt) {
            short8 b1f = *(const short8*)&Bs[0][(nt * 16 + l16) * 40 + q * 8];
            acc[0][nt] = __builtin_amdgcn_mfma_f32_16x16x32_bf16(afr, b1f, acc[0][nt], 0, 0, 0);
            short8 b3f = *(const short8*)&Bs[1][(nt * 16 + l16) * 40 + q * 8];
            acc[1][nt] = __builtin_amdgcn_mfma_f32_16x16x32_bf16(afr, b3f, acc[1][nt], 0, 0, 0);
        }
    }
    // epilogue: he = silu(h1) * h3  (D layout: col=l16, row=q*4+r)
    #pragma unroll
    for (int nt = 0; nt < 8; ++nt) {
        #pragma unroll
        for (int r = 0; r < 4; ++r) {
            int mrow = wave * 16 + q * 4 + r;
            if (my0 + mrow < cnt) {
                float h1 = acc[0][nt][r];
                float h3 = acc[1][nt][r];
                float v  = (h1 / (1.f + __expf(-h1))) * h3;
                he[(size_t)(base + mrow) * HID_ + n0 + nt * 16 + l16] = f2bf(v);
            }
        }
    }
}

// ------------------- MoE phase B: out += g * (he @ W2), bf16 MFMA + f32 atomics
// grid (DIM/128, 128, 9)
__global__ __launch_bounds__(256) void moe_y_kernel(const int* __restrict__ flag,
                                                    const u16* __restrict__ he,
                                                    const float* __restrict__ w2,
                                                    const float* __restrict__ sw2,
                                                    const int* __restrict__ list,
                                                    const int* __restrict__ counts,
                                                    const int* __restrict__ offs,
                                                    const float* __restrict__ egw,
                                                    float* __restrict__ out)
{
    if (*flag != DT_F32) return;
    int e   = blockIdx.z;
    int cnt = (e < 8) ? counts[e] : T_;
    int my0 = blockIdx.y * 64;
    if (my0 >= cnt) return;
    int d0   = blockIdx.x * 128;
    int base = ((e < 8) ? offs[e] : 2 * T_) + my0;
    const float* W2 = (e < 8) ? w2 + (size_t)e * HID_ * DIM_ : sw2;

    __shared__ int   stok[64];
    __shared__ float sg[64];
    __shared__ u16   Bs[128 * 40];

    int t = threadIdx.x;
    if (t < 64) {
        int m  = my0 + t;
        int mm = m < cnt ? m : cnt - 1;
        if (e < 8) {
            int s = list[offs[e] + mm];
            stok[t] = s >> 1; sg[t] = egw[s];
        } else {
            stok[t] = mm; sg[t] = 1.f;
        }
    }
    __syncthreads();

    int wave = t >> 6, lane = t & 63;
    int q = lane >> 4, l16 = lane & 15;
    const u16* arow = he + (size_t)(base + wave * 16 + l16) * HID_;

    int kp = t & 15;
    int ng = t >> 4;

    f32x4 acc[8];
    #pragma unroll
    for (int nt = 0; nt < 8; ++nt) acc[nt] = (f32x4){0.f, 0.f, 0.f, 0.f};

    for (int h0 = 0; h0 < HID_; h0 += 32) {
        __syncthreads();
        const float* W = W2 + (size_t)(h0 + 2 * kp) * DIM_ + d0 + 8 * ng;
        float4 a0 = *(const float4*)(W);
        float4 a1 = *(const float4*)(W + 4);
        float4 b0 = *(const float4*)(W + DIM_);
        float4 b1 = *(const float4*)(W + DIM_ + 4);
        u32* dst = (u32*)Bs + kp;
        dst[(8 * ng + 0) * 20] = pack2(a0.x, b0.x);
        dst[(8 * ng + 1) * 20] = pack2(a0.y, b0.y);
        dst[(8 * ng + 2) * 20] = pack2(a0.z, b0.z);
        dst[(8 * ng + 3) * 20] = pack2(a0.w, b0.w);
        dst[(8 * ng + 4) * 20] = pack2(a1.x, b1.x);
        dst[(8 * ng + 5) * 20] = pack2(a1.y, b1.y);
        dst[(8 * ng + 6) * 20] = pack2(a1.z, b1.z);
        dst[(8 * ng + 7) * 20] = pack2(a1.w, b1.w);
        __syncthreads();
        short8 afr = *(const short8*)(arow + h0 + q * 8);
        #pragma unroll
        for (int nt = 0; nt < 8; ++nt) {
            short8 bf = *(const short8*)&Bs[(nt * 16 + l16) * 40 + q * 8];
            acc[nt] = __builtin_amdgcn_mfma_f32_16x16x32_bf16(afr, bf, acc[nt], 0, 0, 0);
        }
    }
    #pragma unroll
    for (int r = 0; r < 4; ++r) {
        int mrow = wave * 16 + q * 4 + r;
        if (my0 + mrow < cnt) {
            int   tok = stok[mrow];
            float g   = sg[mrow];
            float* orow = out + (size_t)tok * DIM_ + d0 + l16;
            #pragma unroll
            for (int nt = 0; nt < 8; ++nt)
                unsafeAtomicAdd(orow + nt * 16, g * acc[nt][r]);
        }
    }
}

// --------------- old per-token MoE: bf16-external insurance path only
template<typename T>
__global__ __launch_bounds__(256) void moe_kernel(const int* __restrict__ flag,
                                                  const float* __restrict__ h2,
                                                  const float* __restrict__ x1,
                                                  const T* __restrict__ w1,
                                                  const T* __restrict__ w2,
                                                  const T* __restrict__ w3,
                                                  const T* __restrict__ sw1,
                                                  const T* __restrict__ sw2,
                                                  const T* __restrict__ sw3,
                                                  const int* __restrict__ eidx,
                                                  const float* __restrict__ egw,
                                                  T* __restrict__ out)
{
    if (*flag != dtid<T>::v) return;
    int t = blockIdx.x;
    int j = threadIdx.x;
    __shared__ float sx[DIM_];
    __shared__ float she[HID_];
    for (int d = j; d < DIM_; d += 256)
        sx[d] = h2[(size_t)t * DIM_ + d];
    __syncthreads();

    float y[8] = {};
    for (int pass = 0; pass < 3; ++pass) {
        const T *W1, *W2, *W3; float g;
        if (pass < 2) {
            int e = eidx[t * 2 + pass] & 7;
            g = egw[t * 2 + pass];
            W1 = w1 + (size_t)e * DIM_ * HID_;
            W3 = w3 + (size_t)e * DIM_ * HID_;
            W2 = w2 + (size_t)e * HID_ * DIM_;
        } else {
            W1 = sw1; W3 = sw3; W2 = sw2; g = 1.f;
        }
        float a1[4] = {}, a3[4] = {};
        for (int d = 0; d < DIM_; ++d) {
            float xd = sx[d];
            const T* r1 = W1 + (size_t)d * HID_;
            const T* r3 = W3 + (size_t)d * HID_;
            #pragma unroll
            for (int i = 0; i < 4; ++i) {
                a1[i] += xd * ldf(r1 + j + 256 * i);
                a3[i] += xd * ldf(r3 + j + 256 * i);
            }
        }
        #pragma unroll
        for (int i = 0; i < 4; ++i) {
            float h1 = a1[i];
            she[j + 256 * i] = g * (h1 / (1.f + __expf(-h1))) * a3[i];
        }
        __syncthreads();
        for (int hh = 0; hh < HID_; ++hh) {
            float hv = she[hh];
            const T* r2 = W2 + (size_t)hh * DIM_;
            #pragma unroll
            for (int i = 0; i < 8; ++i) y[i] += hv * ldf(r2 + j + 256 * i);
        }
        __syncthreads();
    }
    #pragma unroll
    for (int i = 0; i < 8; ++i) {
        size_t idx = (size_t)t * DIM_ + j + 256 * i;
        stf(out + idx, y[i] + x1[idx]);
    }
}

// ================================================================ launch
extern "C" void kernel_launch(void* const* d_in, const int* in_sizes, int n_in,
                              void* d_out, int out_size, void* d_ws, size_t ws_size,
                              hipStream_t stream)
{
    const size_t TD  = (size_t)T_ * DIM_;            // 8.4M elems
    const size_t TKV = (size_t)T_ * NKV_ * HD_;      // 2.1M elems

    char* ws = (char*)d_ws;
    int*   flag   = (int*)ws;   ws += 16;
    int*   counts = (int*)ws;   ws += 16 * 4;        // counts[16]
    int*   cursor = counts + 16;                     // (part of same 32-int block? no)
    ws += 16 * 4;                                    // cursor[16]
    int*   offs   = (int*)ws;   ws += 16 * 4;
    int*   eidx   = (int*)ws;   ws += (size_t)T_ * 2 * 4;
    float* egw    = (float*)ws; ws += (size_t)T_ * 2 * 4;
    int*   list   = (int*)ws;   ws += (size_t)T_ * 2 * 4;
    float* bufA   = (float*)ws; ws += TD * 4;        // h, then h2
    float* bufB   = (float*)ws; ws += TD * 4;        // q/attn-out; he overlaps after
    u16*   he     = (u16*)bufB;                      // 12288*1024 bf16 = 25.2MB <= 33.5MB
    // bf16-external-only staging (never touched in fp32 mode):
    float* bufKV  = (float*)ws; ws += 2 * TKV * 4;
    float* bufX1f = (float*)ws; ws += TD * 4;

    detect_kernel<<<1, 1, 0, stream>>>((const u32*)d_in[1], flag);
    init_kernel<<<1, 64, 0, stream>>>(counts);

    dim3 gq(DIM_ / 128, T_ / 128);
    dim3 gkv((NKV_ * HD_) / 128, T_ / 128);
    int qpairs = T_ * NH_ * (HD_ / 2);
    int kpairs = T_ * NKV_ * (HD_ / 2);

    #define FOR_DTYPE(T)                                                          \
    {                                                                             \
        const T* x      = (const T*)d_in[0];                                      \
        const T* fcos   = (const T*)d_in[1];                                      \
        const T* fsin   = (const T*)d_in[2];                                      \
        const T* attn_w = (const T*)d_in[3];                                      \
        const T* ffn_w  = (const T*)d_in[4];                                      \
        const T* wq     = (const T*)d_in[5];                                      \
        const T* wk     = (const T*)d_in[6];                                      \
        const T* wv     = (const T*)d_in[7];                                      \
        const T* wo     = (const T*)d_in[8];                                      \
        const T* gate_w = (const T*)d_in[9];                                      \
        T* out_x = (T*)d_out;                                                     \
        T* out_k = out_x + TD;                                                    \
        T* out_v = out_k + TKV;                                                   \
        const bool isF32 = (dtid<T>::v == DT_F32);                                \
        float* kf  = isF32 ? (float*)out_k : bufKV;                               \
        float* vf  = isF32 ? (float*)out_v : bufKV + TKV;                         \
        float* x1f = isF32 ? (float*)out_x : bufX1f;                              \
        rmsnorm_kernel<T, T><<<T_, 256, 0, stream>>>(flag, x, attn_w, bufA);      \
        gemm_kernel<T><<<gq,  256, 0, stream>>>(flag, bufA, wq, bufB,             \
                                                (const T*)nullptr, T_, DIM_, DIM_);\
        gemm_kernel<T><<<gkv, 256, 0, stream>>>(flag, bufA, wk, kf,               \
                                                (const T*)nullptr,                \
                                                T_, NKV_ * HD_, DIM_);            \
        gemm_kernel<T><<<gkv, 256, 0, stream>>>(flag, bufA, wv, vf,               \
                                                (const T*)nullptr,                \
                                                T_, NKV_ * HD_, DIM_);            \
        rope_kernel<T><<<(qpairs + 255) / 256, 256, 0, stream>>>(                 \
            flag, bufB, fcos, fsin, NH_, qpairs);                                 \
        rope_kernel<T><<<(kpairs + 255) / 256, 256, 0, stream>>>(                 \
            flag, kf, fcos, fsin, NKV_, kpairs);                                  \
        if (!isF32) {                                                             \
            cast_kernel<<<(int)((TKV + 255) / 256), 256, 0, stream>>>(            \
                flag, kf, (u16*)out_k, (int)TKV);                                 \
            cast_kernel<<<(int)((TKV + 255) / 256), 256, 0, stream>>>(            \
                flag, vf, (u16*)out_v, (int)TKV);                                 \
        }                                                                         \
        attn_kernel<<<B_ * NH_ * S_, 64, 0, stream>>>(flag, dtid<T>::v,           \
                                                      bufB, kf, vf);              \
        /* x1 = x + attn @ wo (fp32: straight into d_out) */                      \
        gemm_kernel<T><<<gq, 256, 0, stream>>>(flag, bufB, wo, x1f, x,            \
                                               T_, DIM_, DIM_);                   \
        /* h2 = rmsnorm(x1) -> bufA (bufA's h is dead) */                         \
        rmsnorm_kernel<float, T><<<T_, 256, 0, stream>>>(flag, x1f, ffn_w, bufA); \
        gate_kernel<T><<<T_, 64, 0, stream>>>(flag, bufA, gate_w, eidx, egw,      \
                                              counts);                            \
    }

    FOR_DTYPE(float)
    FOR_DTYPE(u16)
    #undef FOR_DTYPE

    // routing bookkeeping (valid for whichever gate ran)
    offs_kernel<<<1, 1, 0, stream>>>(counts, offs);
    scatter_kernel<<<(T_ * 2 + 255) / 256, 256, 0, stream>>>(eidx, offs, cursor, list);

    // fp32 path: grouped bf16-MFMA MoE, atomically accumulated onto x1 in d_out
    {
        const float* w1  = (const float*)d_in[10];
        const float* w2  = (const float*)d_in[11];
        const float* w3  = (const float*)d_in[12];
        const float* sw1 = (const float*)d_in[13];
        const float* sw2 = (const float*)d_in[14];
        const float* sw3 = (const float*)d_in[15];
        dim3 ga(HID_ / 128, 128, 9);
        dim3 gb(DIM_ / 128, 128, 9);
        moe_h_kernel<<<ga, 256, 0, stream>>>(flag, bufA, w1, w3, sw1, sw3,
                                             list, counts, offs, he);
        moe_y_kernel<<<gb, 256, 0, stream>>>(flag, he, w2, sw2,
                                             list, counts, offs, egw,
                                             (float*)d_out);
    }

    // bf16-external insurance path: per-token MoE with fused residual
    moe_kernel<u16><<<T_, 256, 0, stream>>>(flag, bufA, bufX1f,
                                            (const u16*)d_in[10], (const u16*)d_in[11],
                                            (const u16*)d_in[12], (const u16*)d_in[13],
                                            (const u16*)d_in[14], (const u16*)d_in[15],
                                            eidx, egw, (u16*)d_out);
}

// Round 2
// 2855.479 us; speedup vs baseline: 2.5244x; 2.5244x over previous
//
#include <hip/hip_runtime.h>
#include <hip/hip_bf16.h>

// PK1Block: B=2 S=2048 DIM=2048 NH=16 NKV=4 HD=128 NE=8 TOPK=2 HID=SHID=1024
// External dtype: fp32 (confirmed R4). Pre-gate chain stays fp32-ACCURATE
// (routing flips at ~0.003 logit noise). Attention (R6): split-bf16 (hi/lo)
// MFMA flash attention -- 3 MFMAs per product give ~1e-5 rel error, safe for
// routing. Was: serial scalar flash (5.4ms, MfmaUtil=0, dep-chain bound).
// Post-gate MoE = expert-grouped bf16 MFMA GEMMs.
#define B_    2
#define S_    2048
#define DIM_  2048
#define NH_   16
#define NKV_  4
#define HD_   128
#define NE_   8
#define HID_  1024
#define T_    (B_*S_)          // 4096 tokens

typedef unsigned short u16;
typedef unsigned int   u32;

#define DT_BF16 1
#define DT_F32  2

template<typename T> struct dtid;
template<> struct dtid<float> { static constexpr int v = DT_F32;  };
template<> struct dtid<u16>   { static constexpr int v = DT_BF16; };

typedef __attribute__((ext_vector_type(8))) short short8;   // 8 x bf16
typedef __attribute__((ext_vector_type(4))) float f32x4;
typedef __attribute__((ext_vector_type(4))) u32   u32x4;

__device__ __forceinline__ float u2f(u16 u) {
    union { u32 i; float f; } v; v.i = ((u32)u) << 16; return v.f;
}
__device__ __forceinline__ u16 f2bf(float f) {
    union { float f; u32 i; } v; v.f = f;
    u32 x = v.i;
    return (u16)((x + 0x7fffu + ((x >> 16) & 1u)) >> 16);   // RNE
}
__device__ __forceinline__ u32 pack2(float lo, float hi) {
    return (u32)f2bf(lo) | ((u32)f2bf(hi) << 16);
}

template<typename T> __device__ __forceinline__ float ldf(const T* p);
template<> __device__ __forceinline__ float ldf<float>(const float* p) { return *p; }
template<> __device__ __forceinline__ float ldf<u16>(const u16* p)     { return u2f(*p); }

template<typename T> __device__ __forceinline__ void stf(T* p, float v);
template<> __device__ __forceinline__ void stf<float>(float* p, float v) { *p = v; }
template<> __device__ __forceinline__ void stf<u16>(u16* p, float v)     { *p = f2bf(v); }

template<typename T> __device__ __forceinline__ float4 ld4(const T* p);
template<> __device__ __forceinline__ float4 ld4<float>(const float* p) {
    return *(const float4*)p;
}
template<> __device__ __forceinline__ float4 ld4<u16>(const u16* p) {
    ushort4 q = *(const ushort4*)p;
    return make_float4(u2f(q.x), u2f(q.y), u2f(q.z), u2f(q.w));
}

// ---------------------------------------------------------------- dtype detect
__global__ void detect_kernel(const u32* __restrict__ fcos_words,
                              int* __restrict__ flag)
{
    *flag = (fcos_words[0] == 0x3F800000u) ? DT_F32 : DT_BF16;
}

__global__ void init_kernel(int* __restrict__ counts)   // counts[16]+cursor[16]
{
    if (threadIdx.x < 32) counts[threadIdx.x] = 0;
}

// ------------------------------------------------- RMSNorm: IT in -> fp32 out
template<typename IT, typename WT>
__global__ __launch_bounds__(256) void rmsnorm_kernel(const int* __restrict__ flag,
                                                      const IT* __restrict__ xin,
                                                      const WT* __restrict__ w,
                                                      float* __restrict__ out)
{
    if (*flag != dtid<WT>::v) return;
    int t = blockIdx.x;
    const IT* xb = xin + (size_t)t * DIM_;
    float ss = 0.f;
    for (int d = threadIdx.x; d < DIM_; d += 256) {
        float v = ldf(xb + d);
        ss += v * v;
    }
    #pragma unroll
    for (int o = 32; o > 0; o >>= 1) ss += __shfl_xor(ss, o);
    __shared__ float red[4];
    if ((threadIdx.x & 63) == 0) red[threadIdx.x >> 6] = ss;
    __syncthreads();
    float tot = red[0] + red[1] + red[2] + red[3];
    float inv = rsqrtf(tot * (1.0f / DIM_) + 1e-6f);
    for (int d = threadIdx.x; d < DIM_; d += 256)
        out[(size_t)t * DIM_ + d] = ldf(xb + d) * inv * ldf(w + d);
}

// ---------------------- GEMM: A(fp32 ws) @ B(T) -> CF(fp32) [+resid(T)]
// 128x128 tile, 256 threads, 8x8 per thread. k-major LDS, b128 fragments.
template<typename T>
__global__ __launch_bounds__(256) void gemm_kernel(const int* __restrict__ flag,
                                                   const float* __restrict__ A,
                                                   const T* __restrict__ Bw,
                                                   float* __restrict__ CF,
                                                   const T* __restrict__ resid,
                                                   int M, int N, int K)
{
    if (*flag != dtid<T>::v) return;
    __shared__ float As[16][132];
    __shared__ float Bs[16][132];
    int t  = threadIdx.x;
    int bm = blockIdx.y, bn = blockIdx.x;

    int ar = t >> 2;             // A row within tile: 0..63 (and +64)
    int ak = (t & 3) << 2;       // A k-offset: 0,4,8,12
    int bkr = t >> 4;            // B k-row: 0..15
    int bc  = (t & 15) << 3;     // B col-offset: 0..120

    const float* Ap0 = A + (size_t)(bm * 128 + ar) * K + ak;
    const float* Ap1 = Ap0 + (size_t)64 * K;
    const T*     Bp  = Bw + (size_t)bkr * N + bn * 128 + bc;

    int lane = t & 63, w = t >> 6;
    int mi = ((lane & 7) + ((w & 1) << 3)) << 3;   // 0..120
    int ni = ((lane >> 3) + ((w >> 1) << 3)) << 3; // 0..120

    float acc[8][8] = {};

    float4 pa0 = *(const float4*)(Ap0);
    float4 pa1 = *(const float4*)(Ap1);
    float4 pb0 = ld4(Bp);
    float4 pb1 = ld4(Bp + 4);

    for (int k0 = 0; k0 < K; k0 += 16) {
        As[ak + 0][ar]      = pa0.x; As[ak + 1][ar]      = pa0.y;
        As[ak + 2][ar]      = pa0.z; As[ak + 3][ar]      = pa0.w;
        As[ak + 0][ar + 64] = pa1.x; As[ak + 1][ar + 64] = pa1.y;
        As[ak + 2][ar + 64] = pa1.z; As[ak + 3][ar + 64] = pa1.w;
        *(float4*)&Bs[bkr][bc]     = pb0;
        *(float4*)&Bs[bkr][bc + 4] = pb1;
        __syncthreads();

        if (k0 + 16 < K) {
            pa0 = *(const float4*)(Ap0 + k0 + 16);
            pa1 = *(const float4*)(Ap1 + k0 + 16);
            pb0 = ld4(Bp + (size_t)(k0 + 16) * N);
            pb1 = ld4(Bp + (size_t)(k0 + 16) * N + 4);
        }

        #pragma unroll
        for (int kk = 0; kk < 16; ++kk) {
            float4 a0 = *(const float4*)&As[kk][mi];
            float4 a1 = *(const float4*)&As[kk][mi + 4];
            float4 b0 = *(const float4*)&Bs[kk][ni];
            float4 b1 = *(const float4*)&Bs[kk][ni + 4];
            float a[8] = { a0.x, a0.y, a0.z, a0.w, a1.x, a1.y, a1.z, a1.w };
            float b[8] = { b0.x, b0.y, b0.z, b0.w, b1.x, b1.y, b1.z, b1.w };
            #pragma unroll
            for (int i = 0; i < 8; ++i)
                #pragma unroll
                for (int j = 0; j < 8; ++j) acc[i][j] += a[i] * b[j];
        }
        __syncthreads();
    }

    #pragma unroll
    for (int i = 0; i < 8; ++i) {
        size_t off = (size_t)(bm * 128 + mi + i) * N + bn * 128 + ni;
        #pragma unroll
        for (int j = 0; j < 8; ++j) {
            float c = acc[i][j];
            if (resid) c += ldf(resid + off + j);
            CF[off + j] = c;
        }
    }
}

// ---------------------------------------------------------------- RoPE (fp32, in place)
template<typename FT>
__global__ __launch_bounds__(256) void rope_kernel(const int* __restrict__ flag,
                                                   float* __restrict__ t,
                                                   const FT* __restrict__ fc,
                                                   const FT* __restrict__ fs,
                                                   int nheads, int npairs)
{
    if (*flag != dtid<FT>::v) return;
    int gid = blockIdx.x * 256 + threadIdx.x;
    if (gid >= npairs) return;
    int i    = gid & 63;
    int rest = gid >> 6;
    int h    = rest % nheads;
    int tok  = rest / nheads;
    int spos = tok & (S_ - 1);
    float c = ldf(fc + spos * 64 + i);
    float s = ldf(fs + spos * 64 + i);
    size_t base = ((size_t)tok * nheads + h) * HD_ + 2 * i;
    float t1 = t[base], t2 = t[base + 1];
    t[base]     = t1 * c - t2 * s;
    t[base + 1] = t1 * s + t2 * c;
}

// ---------------------------------------------------------------- fp32 -> bf16 cast
__global__ __launch_bounds__(256) void cast_kernel(const int* __restrict__ flag,
                                                   const float* __restrict__ src,
                                                   u16* __restrict__ dst, int n)
{
    if (*flag != DT_BF16) return;
    int i = blockIdx.x * 256 + threadIdx.x;
    if (i < n) dst[i] = f2bf(src[i]);
}

// --------------------------- Flash attention, split-bf16 MFMA (fp32-accurate)
// Block: 4 waves, 64 queries of one head (qt*64..+63); wave w owns 16 queries.
// J-tiles of 32. Swapped QK (S^T = mfma(K,Q)) so softmax column = lane's l16.
// Split fp32 = bf16hi + bf16lo; 3 MFMAs per product -> ~1e-5 rel error.
__global__ __launch_bounds__(256) void attn_mfma_kernel(const int* __restrict__ flag,
                                                        int want,
                                                        float* __restrict__ q,
                                                        const float* __restrict__ k,
                                                        const float* __restrict__ v)
{
    if (*flag != want) return;
    int qt = blockIdx.x;          // 0..31 (query tile of 64)
    int h  = blockIdx.y;          // 0..15
    int b  = blockIdx.z;          // 0..1
    int kvh = h >> 2;
    int t = threadIdx.x;
    int wv = t >> 6, lane = t & 63;
    int qf = lane >> 4, l16 = lane & 15;

    __shared__ u16 Khi[32 * 128];         // [j][d] bf16 hi, 256B rows, XOR-swizzled
    __shared__ u16 Klo[32 * 128];
    __shared__ u16 Vthi[128 * 40];        // [d][j] bf16 hi, pitch 40
    __shared__ u16 Vtlo[128 * 40];
    __shared__ u32 Plds[4][16 * 36];      // per-wave P bounce: [q][j] packed hi|lo

    int q0   = qt * 64;
    int qrow = q0 + wv * 16 + l16;        // this lane's query (softmax column)
    const float* kb = k + (size_t)b * S_ * (NKV_ * HD_) + kvh * HD_;
    const float* vb = v + (size_t)b * S_ * (NKV_ * HD_) + kvh * HD_;

    // ---- Q fragments (B-operand): lane holds Q[qrow][c*32 + qf*8 .. +7] hi/lo
    size_t qbase = ((size_t)(b * S_ + qrow) * NH_ + h) * HD_;
    short8 qhi[4], qlo[4];
    #pragma unroll
    for (int c = 0; c < 4; ++c) {
        const float* qp = q + qbase + c * 32 + qf * 8;
        float4 f0 = *(const float4*)qp;
        float4 f1 = *(const float4*)(qp + 4);
        float xs[8] = { f0.x, f0.y, f0.z, f0.w, f1.x, f1.y, f1.z, f1.w };
        #pragma unroll
        for (int u = 0; u < 8; ++u) {
            u16 hh = f2bf(xs[u]);
            qhi[c][u] = (short)hh;
            qlo[c][u] = (short)f2bf(xs[u] - u2f(hh));
        }
    }

    f32x4 Ot[8];                          // O^T[d = dt*16+qf*4+r][q = l16]
    #pragma unroll
    for (int dt = 0; dt < 8; ++dt) Ot[dt] = (f32x4){0.f, 0.f, 0.f, 0.f};
    float m = -1e30f, l = 0.f;
    const float scale = 0.08838834764831845f;

    // staging thread maps
    int sj  = t >> 3;                     // K: row 0..31
    int sa  = t & 7;                      // K: d-group 0..7 (16 floats each)
    int vjp = t & 15;                     // V: j-pair 0..15
    int vdg = t >> 4;                     // V: d-group 0..15 (8 floats each)

    int ntiles = (q0 + 64) >> 5;          // qt*2 + 2
    for (int tile = 0; tile < ntiles; ++tile) {
        int jt0 = tile << 5;
        __syncthreads();
        // ---- stage K tile (32x128) hi/lo, swizzled: byte ^= (j&7)<<4
        {
            const float* krow = kb + (size_t)(jt0 + sj) * (NKV_ * HD_);
            #pragma unroll
            for (int i = 0; i < 4; ++i) {
                int d = sa * 16 + i * 4;
                float4 f = *(const float4*)(krow + d);
                ushort4 hi, lo;
                hi.x = f2bf(f.x); lo.x = f2bf(f.x - u2f(hi.x));
                hi.y = f2bf(f.y); lo.y = f2bf(f.y - u2f(hi.y));
                hi.z = f2bf(f.z); lo.z = f2bf(f.z - u2f(hi.z));
                hi.w = f2bf(f.w); lo.w = f2bf(f.w - u2f(hi.w));
                int bix = (d * 2) ^ ((sj & 7) << 4);
                *(ushort4*)&Khi[sj * 128 + (bix >> 1)] = hi;
                *(ushort4*)&Klo[sj * 128 + (bix >> 1)] = lo;
            }
        }
        // ---- stage V transposed (Vt[d][j]) hi/lo
        {
            #pragma unroll
            for (int p = 0; p < 2; ++p) {
                int d = vdg * 8 + p * 4;
                const float* v0 = vb + (size_t)(jt0 + 2 * vjp) * (NKV_ * HD_) + d;
                const float* v1 = v0 + NKV_ * HD_;
                float4 a = *(const float4*)v0;
                float4 c4 = *(const float4*)v1;
                float aa[4] = { a.x, a.y, a.z, a.w };
                float bb[4] = { c4.x, c4.y, c4.z, c4.w };
                #pragma unroll
                for (int i = 0; i < 4; ++i) {
                    int r = d + i;
                    u16 h0 = f2bf(aa[i]); u16 l0 = f2bf(aa[i] - u2f(h0));
                    u16 h1 = f2bf(bb[i]); u16 l1 = f2bf(bb[i] - u2f(h1));
                    *(u32*)&Vthi[r * 40 + vjp * 2] = (u32)h0 | ((u32)h1 << 16);
                    *(u32*)&Vtlo[r * 40 + vjp * 2] = (u32)l0 | ((u32)l1 << 16);
                }
            }
        }
        __syncthreads();

        // ---- QK^T: S^T[j][q], 2 j-subtiles x 4 d-steps x 3 split-MFMAs
        f32x4 st[2];
        st[0] = (f32x4){0.f, 0.f, 0.f, 0.f};
        st[1] = (f32x4){0.f, 0.f, 0.f, 0.f};
        #pragma unroll
        for (int jt2 = 0; jt2 < 2; ++jt2) {
            int row = jt2 * 16 + l16;
            #pragma unroll
            for (int c = 0; c < 4; ++c) {
                int bix = (c * 64 + qf * 16) ^ ((l16 & 7) << 4);
                short8 khi = *(const short8*)&Khi[row * 128 + (bix >> 1)];
                short8 klo = *(const short8*)&Klo[row * 128 + (bix >> 1)];
                st[jt2] = __builtin_amdgcn_mfma_f32_16x16x32_bf16(khi, qhi[c], st[jt2], 0, 0, 0);
                st[jt2] = __builtin_amdgcn_mfma_f32_16x16x32_bf16(khi, qlo[c], st[jt2], 0, 0, 0);
                st[jt2] = __builtin_amdgcn_mfma_f32_16x16x32_bf16(klo, qhi[c], st[jt2], 0, 0, 0);
            }
        }

        // ---- mask + online softmax (column q = l16, rows j across qf groups)
        float pv[8];
        float pmax = -1e30f;
        #pragma unroll
        for (int jt2 = 0; jt2 < 2; ++jt2) {
            #pragma unroll
            for (int r = 0; r < 4; ++r) {
                int j = jt0 + jt2 * 16 + qf * 4 + r;
                float s = st[jt2][r] * scale;
                if (j > qrow) s = -1e30f;
                pv[jt2 * 4 + r] = s;
                pmax = fmaxf(pmax, s);
            }
        }
        pmax = fmaxf(pmax, __shfl_xor(pmax, 16));
        pmax = fmaxf(pmax, __shfl_xor(pmax, 32));
        float mn    = fmaxf(m, pmax);
        float alpha = __expf(m - mn);
        m = mn;
        float rs = 0.f;
        u32 pw[8];
        #pragma unroll
        for (int i = 0; i < 8; ++i) {
            float p = __expf(pv[i] - mn);
            rs += p;
            u16 ph = f2bf(p);
            pw[i] = (u32)ph | ((u32)f2bf(p - u2f(ph)) << 16);
        }
        rs += __shfl_xor(rs, 16);
        rs += __shfl_xor(rs, 32);
        l = l * alpha + rs;

        // ---- bounce P through per-wave LDS to B-fragment layout
        u32* pl = &Plds[wv][l16 * 36];
        *(u32x4*)&pl[qf * 4]      = (u32x4){ pw[0], pw[1], pw[2], pw[3] };
        *(u32x4*)&pl[16 + qf * 4] = (u32x4){ pw[4], pw[5], pw[6], pw[7] };
        asm volatile("s_waitcnt lgkmcnt(0)" ::: "memory");
        __builtin_amdgcn_sched_barrier(0);
        u32x4 w0 = *(const u32x4*)&Plds[wv][l16 * 36 + qf * 8];
        u32x4 w1 = *(const u32x4*)&Plds[wv][l16 * 36 + qf * 8 + 4];
        short8 phi, plo;
        #pragma unroll
        for (int u = 0; u < 4; ++u) {
            phi[u]     = (short)(w0[u] & 0xffffu); plo[u]     = (short)(w0[u] >> 16);
            phi[4 + u] = (short)(w1[u] & 0xffffu); plo[4 + u] = (short)(w1[u] >> 16);
        }

        // ---- rescale O by alpha, then PV: O^T += V^T-frag x P-frag
        #pragma unroll
        for (int dt = 0; dt < 8; ++dt) {
            #pragma unroll
            for (int r = 0; r < 4; ++r) Ot[dt][r] *= alpha;
        }
        #pragma unroll
        for (int dt = 0; dt < 8; ++dt) {
            int row = dt * 16 + l16;
            short8 vhi = *(const short8*)&Vthi[row * 40 + qf * 8];
            short8 vlo = *(const short8*)&Vtlo[row * 40 + qf * 8];
            Ot[dt] = __builtin_amdgcn_mfma_f32_16x16x32_bf16(vhi, phi, Ot[dt], 0, 0, 0);
            Ot[dt] = __builtin_amdgcn_mfma_f32_16x16x32_bf16(vhi, plo, Ot[dt], 0, 0, 0);
            Ot[dt] = __builtin_amdgcn_mfma_f32_16x16x32_bf16(vlo, phi, Ot[dt], 0, 0, 0);
        }
    }

    // ---- epilogue: O[q][d] = O^T / l, written in place over q
    float invl = 1.f / l;
    #pragma unroll
    for (int dt = 0; dt < 8; ++dt) {
        #pragma unroll
        for (int r = 0; r < 4; ++r)
            q[qbase + dt * 16 + qf * 4 + r] = Ot[dt][r] * invl;
    }
}

// ---------------------------------------------------------------- top-2 gate
template<typename T>
__global__ __launch_bounds__(64) void gate_kernel(const int* __restrict__ flag,
                                                  const float* __restrict__ xt,
                                                  const T* __restrict__ gw,
                                                  int* __restrict__ eidx,
                                                  float* __restrict__ egw,
                                                  int* __restrict__ counts)
{
    if (*flag != dtid<T>::v) return;
    int t = blockIdx.x, lane = threadIdx.x;
    float acc[NE_] = {};
    const float* xr = xt + (size_t)t * DIM_;
    for (int d = lane; d < DIM_; d += 64) {
        float xd = xr[d];
        #pragma unroll
        for (int e = 0; e < NE_; ++e) acc[e] += xd * ldf(gw + d * NE_ + e);
    }
    #pragma unroll
    for (int e = 0; e < NE_; ++e)
        #pragma unroll
        for (int off = 32; off > 0; off >>= 1) acc[e] += __shfl_xor(acc[e], off);
    if (lane == 0) {
        int i0 = 0; float m0 = acc[0];
        #pragma unroll
        for (int e = 1; e < NE_; ++e) if (acc[e] > m0) { m0 = acc[e]; i0 = e; }
        int i1 = (i0 == 0) ? 1 : 0; float m1 = acc[i1];
        for (int e = i1 + 1; e < NE_; ++e)
            if (e != i0 && acc[e] > m1) { m1 = acc[e]; i1 = e; }
        float e1  = __expf(m1 - m0);
        float inv = 1.f / (1.f + e1);
        eidx[t * 2] = i0; eidx[t * 2 + 1] = i1;
        egw [t * 2] = inv; egw [t * 2 + 1] = e1 * inv;
        atomicAdd(&counts[i0], 1);
        atomicAdd(&counts[i1], 1);
    }
}

__global__ void offs_kernel(const int* __restrict__ counts, int* __restrict__ offs)
{
    if (threadIdx.x == 0) {
        int off = 0;
        for (int e = 0; e < NE_; ++e) { offs[e] = off; off += counts[e]; }
    }
}

__global__ __launch_bounds__(256) void scatter_kernel(const int* __restrict__ eidx,
                                                      const int* __restrict__ offs,
                                                      int* __restrict__ cursor,
                                                      int* __restrict__ list)
{
    int s = blockIdx.x * 256 + threadIdx.x;
    if (s >= T_ * 2) return;
    int e = eidx[s] & 7;
    int pos = atomicAdd(&cursor[e], 1);
    list[offs[e] + pos] = s;
}

// ------------------- MoE phase A: he = silu(X@W1) * (X@W3), bf16 MFMA
__global__ __launch_bounds__(256) void moe_h_kernel(const int* __restrict__ flag,
                                                    const float* __restrict__ h2,
                                                    const float* __restrict__ w1,
                                                    const float* __restrict__ w3,
                                                    const float* __restrict__ sw1,
                                                    const float* __restrict__ sw3,
                                                    const int* __restrict__ list,
                                                    const int* __restrict__ counts,
                                                    const int* __restrict__ offs,
                                                    u16* __restrict__ he)
{
    if (*flag != DT_F32) return;
    int e   = blockIdx.z;
    int cnt = (e < 8) ? counts[e] : T_;
    int my0 = blockIdx.y * 64;
    if (my0 >= cnt) return;
    int n0   = blockIdx.x * 128;
    int base = ((e < 8) ? offs[e] : 2 * T_) + my0;
    const float* W1 = (e < 8) ? w1 + (size_t)e * DIM_ * HID_ : sw1;
    const float* W3 = (e < 8) ? w3 + (size_t)e * DIM_ * HID_ : sw3;

    __shared__ int toks[64];
    __shared__ u16 Bs[2][128 * 40];

    int t = threadIdx.x;
    if (t < 64) {
        int m  = my0 + t;
        int mm = m < cnt ? m : cnt - 1;
        toks[t] = (e < 8) ? (list[offs[e] + mm] >> 1) : mm;
    }
    __syncthreads();

    int wave = t >> 6, lane = t & 63;
    int q = lane >> 4, l16 = lane & 15;
    int mytok = toks[wave * 16 + l16];
    const float* arow = h2 + (size_t)mytok * DIM_;

    int kp = t & 15;
    int ng = t >> 4;

    f32x4 acc[2][8];
    #pragma unroll
    for (int m_ = 0; m_ < 2; ++m_)
        #pragma unroll
        for (int nt = 0; nt < 8; ++nt) acc[m_][nt] = (f32x4){0.f, 0.f, 0.f, 0.f};

    for (int d0 = 0; d0 < DIM_; d0 += 32) {
        __syncthreads();
        #pragma unroll
        for (int mat = 0; mat < 2; ++mat) {
            const float* W = (mat ? W3 : W1) + (size_t)(d0 + 2 * kp) * HID_ + n0 + 8 * ng;
            float4 a0 = *(const float4*)(W);
            float4 a1 = *(const float4*)(W + 4);
            float4 b0 = *(const float4*)(W + HID_);
            float4 b1 = *(const float4*)(W + HID_ + 4);
            u32* dst = (u32*)Bs[mat] + kp;
            dst[(8 * ng + 0) * 20] = pack2(a0.x, b0.x);
            dst[(8 * ng + 1) * 20] = pack2(a0.y, b0.y);
            dst[(8 * ng + 2) * 20] = pack2(a0.z, b0.z);
            dst[(8 * ng + 3) * 20] = pack2(a0.w, b0.w);
            dst[(8 * ng + 4) * 20] = pack2(a1.x, b1.x);
            dst[(8 * ng + 5) * 20] = pack2(a1.y, b1.y);
            dst[(8 * ng + 6) * 20] = pack2(a1.z, b1.z);
            dst[(8 * ng + 7) * 20] = pack2(a1.w, b1.w);
        }
        __syncthreads();
        const float* ap = arow + d0 + q * 8;
        float4 af0 = *(const float4*)(ap);
        float4 af1 = *(const float4*)(ap + 4);
        short8 afr;
        afr[0] = (short)f2bf(af0.x); afr[1] = (short)f2bf(af0.y);
        afr[2] = (short)f2bf(af0.z); afr[3] = (short)f2bf(af0.w);
        afr[4] = (short)f2bf(af1.x); afr[5] = (short)f2bf(af1.y);
        afr[6] = (short)f2bf(af1.z); afr[7] = (short)f2bf(af1.w);
        #pragma unroll
        for (int nt = 0; nt < 8; ++nt) {
            short8 b1f = *(const short8*)&Bs[0][(nt * 16 + l16) * 40 + q * 8];
            acc[0][nt] = __builtin_amdgcn_mfma_f32_16x16x32_bf16(afr, b1f, acc[0][nt], 0, 0, 0);
            short8 b3f = *(const short8*)&Bs[1][(nt * 16 + l16) * 40 + q * 8];
            acc[1][nt] = __builtin_amdgcn_mfma_f32_16x16x32_bf16(afr, b3f, acc[1][nt], 0, 0, 0);
        }
    }
    #pragma unroll
    for (int nt = 0; nt < 8; ++nt) {
        #pragma unroll
        for (int r = 0; r < 4; ++r) {
            int mrow = wave * 16 + q * 4 + r;
            if (my0 + mrow < cnt) {
                float h1 = acc[0][nt][r];
                float h3 = acc[1][nt][r];
                float v  = (h1 / (1.f + __expf(-h1))) * h3;
                he[(size_t)(base + mrow) * HID_ + n0 + nt * 16 + l16] = f2bf(v);
            }
        }
    }
}

// ------------------- MoE phase B: out += g * (he @ W2), bf16 MFMA + f32 atomics
__global__ __launch_bounds__(256) void moe_y_kernel(const int* __restrict__ flag,
                                                    const u16* __restrict__ he,
                                                    const float* __restrict__ w2,
                                                    const float* __restrict__ sw2,
                                                    const int* __restrict__ list,
                                                    const int* __restrict__ counts,
                                                    const int* __restrict__ offs,
                                                    const float* __restrict__ egw,
                                                    float* __restrict__ out)
{
    if (*flag != DT_F32) return;
    int e   = blockIdx.z;
    int cnt = (e < 8) ? counts[e] : T_;
    int my0 = blockIdx.y * 64;
    if (my0 >= cnt) return;
    int d0   = blockIdx.x * 128;
    int base = ((e < 8) ? offs[e] : 2 * T_) + my0;
    const float* W2 = (e < 8) ? w2 + (size_t)e * HID_ * DIM_ : sw2;

    __shared__ int   stok[64];
    __shared__ float sg[64];
    __shared__ u16   Bs[128 * 40];

    int t = threadIdx.x;
    if (t < 64) {
        int m  = my0 + t;
        int mm = m < cnt ? m : cnt - 1;
        if (e < 8) {
            int s = list[offs[e] + mm];
            stok[t] = s >> 1; sg[t] = egw[s];
        } else {
            stok[t] = mm; sg[t] = 1.f;
        }
    }
    __syncthreads();

    int wave = t >> 6, lane = t & 63;
    int q = lane >> 4, l16 = lane & 15;
    const u16* arow = he + (size_t)(base + wave * 16 + l16) * HID_;

    int kp = t & 15;
    int ng = t >> 4;

    f32x4 acc[8];
    #pragma unroll
    for (int nt = 0; nt < 8; ++nt) acc[nt] = (f32x4){0.f, 0.f, 0.f, 0.f};

    for (int h0 = 0; h0 < HID_; h0 += 32) {
        __syncthreads();
        const float* W = W2 + (size_t)(h0 + 2 * kp) * DIM_ + d0 + 8 * ng;
        float4 a0 = *(const float4*)(W);
        float4 a1 = *(const float4*)(W + 4);
        float4 b0 = *(const float4*)(W + DIM_);
        float4 b1 = *(const float4*)(W + DIM_ + 4);
        u32* dst = (u32*)Bs + kp;
        dst[(8 * ng + 0) * 20] = pack2(a0.x, b0.x);
        dst[(8 * ng + 1) * 20] = pack2(a0.y, b0.y);
        dst[(8 * ng + 2) * 20] = pack2(a0.z, b0.z);
        dst[(8 * ng + 3) * 20] = pack2(a0.w, b0.w);
        dst[(8 * ng + 4) * 20] = pack2(a1.x, b1.x);
        dst[(8 * ng + 5) * 20] = pack2(a1.y, b1.y);
        dst[(8 * ng + 6) * 20] = pack2(a1.z, b1.z);
        dst[(8 * ng + 7) * 20] = pack2(a1.w, b1.w);
        __syncthreads();
        short8 afr = *(const short8*)(arow + h0 + q * 8);
        #pragma unroll
        for (int nt = 0; nt < 8; ++nt) {
            short8 bf = *(const short8*)&Bs[(nt * 16 + l16) * 40 + q * 8];
            acc[nt] = __builtin_amdgcn_mfma_f32_16x16x32_bf16(afr, bf, acc[nt], 0, 0, 0);
        }
    }
    #pragma unroll
    for (int r = 0; r < 4; ++r) {
        int mrow = wave * 16 + q * 4 + r;
        if (my0 + mrow < cnt) {
            int   tok = stok[mrow];
            float g   = sg[mrow];
            float* orow = out + (size_t)tok * DIM_ + d0 + l16;
            #pragma unroll
            for (int nt = 0; nt < 8; ++nt)
                unsafeAtomicAdd(orow + nt * 16, g * acc[nt][r]);
        }
    }
}

// --------------- old per-token MoE: bf16-external insurance path only
template<typename T>
__global__ __launch_bounds__(256) void moe_kernel(const int* __restrict__ flag,
                                                  const float* __restrict__ h2,
                                                  const float* __restrict__ x1,
                                                  const T* __restrict__ w1,
                                                  const T* __restrict__ w2,
                                                  const T* __restrict__ w3,
                                                  const T* __restrict__ sw1,
                                                  const T* __restrict__ sw2,
                                                  const T* __restrict__ sw3,
                                                  const int* __restrict__ eidx,
                                                  const float* __restrict__ egw,
                                                  T* __restrict__ out)
{
    if (*flag != dtid<T>::v) return;
    int t = blockIdx.x;
    int j = threadIdx.x;
    __shared__ float sx[DIM_];
    __shared__ float she[HID_];
    for (int d = j; d < DIM_; d += 256)
        sx[d] = h2[(size_t)t * DIM_ + d];
    __syncthreads();

    float y[8] = {};
    for (int pass = 0; pass < 3; ++pass) {
        const T *W1, *W2, *W3; float g;
        if (pass < 2) {
            int e = eidx[t * 2 + pass] & 7;
            g = egw[t * 2 + pass];
            W1 = w1 + (size_t)e * DIM_ * HID_;
            W3 = w3 + (size_t)e * DIM_ * HID_;
            W2 = w2 + (size_t)e * HID_ * DIM_;
        } else {
            W1 = sw1; W3 = sw3; W2 = sw2; g = 1.f;
        }
        float a1[4] = {}, a3[4] = {};
        for (int d = 0; d < DIM_; ++d) {
            float xd = sx[d];
            const T* r1 = W1 + (size_t)d * HID_;
            const T* r3 = W3 + (size_t)d * HID_;
            #pragma unroll
            for (int i = 0; i < 4; ++i) {
                a1[i] += xd * ldf(r1 + j + 256 * i);
                a3[i] += xd * ldf(r3 + j + 256 * i);
            }
        }
        #pragma unroll
        for (int i = 0; i < 4; ++i) {
            float h1 = a1[i];
            she[j + 256 * i] = g * (h1 / (1.f + __expf(-h1))) * a3[i];
        }
        __syncthreads();
        for (int hh = 0; hh < HID_; ++hh) {
            float hv = she[hh];
            const T* r2 = W2 + (size_t)hh * DIM_;
            #pragma unroll
            for (int i = 0; i < 8; ++i) y[i] += hv * ldf(r2 + j + 256 * i);
        }
        __syncthreads();
    }
    #pragma unroll
    for (int i = 0; i < 8; ++i) {
        size_t idx = (size_t)t * DIM_ + j + 256 * i;
        stf(out + idx, y[i] + x1[idx]);
    }
}

// ================================================================ launch
extern "C" void kernel_launch(void* const* d_in, const int* in_sizes, int n_in,
                              void* d_out, int out_size, void* d_ws, size_t ws_size,
                              hipStream_t stream)
{
    const size_t TD  = (size_t)T_ * DIM_;            // 8.4M elems
    const size_t TKV = (size_t)T_ * NKV_ * HD_;      // 2.1M elems

    char* ws = (char*)d_ws;
    int*   flag   = (int*)ws;   ws += 16;
    int*   counts = (int*)ws;   ws += 16 * 4;        // counts[16]
    int*   cursor = counts + 16;
    ws += 16 * 4;                                    // cursor[16]
    int*   offs   = (int*)ws;   ws += 16 * 4;
    int*   eidx   = (int*)ws;   ws += (size_t)T_ * 2 * 4;
    float* egw    = (float*)ws; ws += (size_t)T_ * 2 * 4;
    int*   list   = (int*)ws;   ws += (size_t)T_ * 2 * 4;
    float* bufA   = (float*)ws; ws += TD * 4;        // h, then h2
    float* bufB   = (float*)ws; ws += TD * 4;        // q/attn-out; he overlaps after
    u16*   he     = (u16*)bufB;
    float* bufKV  = (float*)ws; ws += 2 * TKV * 4;
    float* bufX1f = (float*)ws; ws += TD * 4;

    detect_kernel<<<1, 1, 0, stream>>>((const u32*)d_in[1], flag);
    init_kernel<<<1, 64, 0, stream>>>(counts);

    dim3 gq(DIM_ / 128, T_ / 128);
    dim3 gkv((NKV_ * HD_) / 128, T_ / 128);
    dim3 gattn(S_ / 64, NH_, B_);
    int qpairs = T_ * NH_ * (HD_ / 2);
    int kpairs = T_ * NKV_ * (HD_ / 2);

    #define FOR_DTYPE(T)                                                          \
    {                                                                             \
        const T* x      = (const T*)d_in[0];                                      \
        const T* fcos   = (const T*)d_in[1];                                      \
        const T* fsin   = (const T*)d_in[2];                                      \
        const T* attn_w = (const T*)d_in[3];                                      \
        const T* ffn_w  = (const T*)d_in[4];                                      \
        const T* wq     = (const T*)d_in[5];                                      \
        const T* wk     = (const T*)d_in[6];                                      \
        const T* wv     = (const T*)d_in[7];                                      \
        const T* wo     = (const T*)d_in[8];                                      \
        const T* gate_w = (const T*)d_in[9];                                      \
        T* out_x = (T*)d_out;                                                     \
        T* out_k = out_x + TD;                                                    \
        T* out_v = out_k + TKV;                                                   \
        const bool isF32 = (dtid<T>::v == DT_F32);                                \
        float* kf  = isF32 ? (float*)out_k : bufKV;                               \
        float* vf  = isF32 ? (float*)out_v : bufKV + TKV;                         \
        float* x1f = isF32 ? (float*)out_x : bufX1f;                              \
        rmsnorm_kernel<T, T><<<T_, 256, 0, stream>>>(flag, x, attn_w, bufA);      \
        gemm_kernel<T><<<gq,  256, 0, stream>>>(flag, bufA, wq, bufB,             \
                                                (const T*)nullptr, T_, DIM_, DIM_);\
        gemm_kernel<T><<<gkv, 256, 0, stream>>>(flag, bufA, wk, kf,               \
                                                (const T*)nullptr,                \
                                                T_, NKV_ * HD_, DIM_);            \
        gemm_kernel<T><<<gkv, 256, 0, stream>>>(flag, bufA, wv, vf,               \
                                                (const T*)nullptr,                \
                                                T_, NKV_ * HD_, DIM_);            \
        rope_kernel<T><<<(qpairs + 255) / 256, 256, 0, stream>>>(                 \
            flag, bufB, fcos, fsin, NH_, qpairs);                                 \
        rope_kernel<T><<<(kpairs + 255) / 256, 256, 0, stream>>>(                 \
            flag, kf, fcos, fsin, NKV_, kpairs);                                  \
        if (!isF32) {                                                             \
            cast_kernel<<<(int)((TKV + 255) / 256), 256, 0, stream>>>(            \
                flag, kf, (u16*)out_k, (int)TKV);                                 \
            cast_kernel<<<(int)((TKV + 255) / 256), 256, 0, stream>>>(            \
                flag, vf, (u16*)out_v, (int)TKV);                                 \
        }                                                                         \
        attn_mfma_kernel<<<gattn, 256, 0, stream>>>(flag, dtid<T>::v,             \
                                                    bufB, kf, vf);                \
        gemm_kernel<T><<<gq, 256, 0, stream>>>(flag, bufB, wo, x1f, x,            \
                                               T_, DIM_, DIM_);                   \
        rmsnorm_kernel<float, T><<<T_, 256, 0, stream>>>(flag, x1f, ffn_w, bufA); \
        gate_kernel<T><<<T_, 64, 0, stream>>>(flag, bufA, gate_w, eidx, egw,      \
                                              counts);                            \
    }

    FOR_DTYPE(float)
    FOR_DTYPE(u16)
    #undef FOR_DTYPE

    offs_kernel<<<1, 1, 0, stream>>>(counts, offs);
    scatter_kernel<<<(T_ * 2 + 255) / 256, 256, 0, stream>>>(eidx, offs, cursor, list);

    {
        const float* w1  = (const float*)d_in[10];
        const float* w2  = (const float*)d_in[11];
        const float* w3  = (const float*)d_in[12];
        const float* sw1 = (const float*)d_in[13];
        const float* sw2 = (const float*)d_in[14];
        const float* sw3 = (const float*)d_in[15];
        dim3 ga(HID_ / 128, 128, 9);
        dim3 gb(DIM_ / 128, 128, 9);
        moe_h_kernel<<<ga, 256, 0, stream>>>(flag, bufA, w1, w3, sw1, sw3,
                                             list, counts, offs, he);
        moe_y_kernel<<<gb, 256, 0, stream>>>(flag, he, w2, sw2,
                                             list, counts, offs, egw,
                                             (float*)d_out);
    }

    moe_kernel<u16><<<T_, 256, 0, stream>>>(flag, bufA, bufX1f,
                                            (const u16*)d_in[10], (const u16*)d_in[11],
                                            (const u16*)d_in[12], (const u16*)d_in[13],
                                            (const u16*)d_in[14], (const u16*)d_in[15],
                                            eidx, egw, (u16*)d_out);
}

// Round 3
// 2532.164 us; speedup vs baseline: 2.8467x; 1.1277x over previous
//
#include <hip/hip_runtime.h>
#include <hip/hip_bf16.h>

// PK1Block: B=2 S=2048 DIM=2048 NH=16 NKV=4 HD=128 NE=8 TOPK=2 HID=SHID=1024
// External dtype: fp32 (confirmed R4). Pre-gate chain stays fp32-ACCURATE
// (routing flips at ~0.003 logit noise). Attention: split-bf16 MFMA flash.
// R7: MoE rewritten -- weights pre-transposed to bf16 [n][k] once per launch,
// then moe_h2/moe_y2 are m97-style MFMA GEMMs: global_load_lds (16B, linear
// LDS, source-chunk XOR pre-swizzle for conflict-free b128 reads), BK=64,
// double-buffered, 1 barrier/k-step. Was: 16-way LDS write conflicts
// (SQ_LDS_BANK_CONFLICT=3.9e7) + per-k-step fp32 repack -> MfmaUtil 6.4%.
#define B_    2
#define S_    2048
#define DIM_  2048
#define NH_   16
#define NKV_  4
#define HD_   128
#define NE_   8
#define HID_  1024
#define T_    (B_*S_)          // 4096 tokens

typedef unsigned short u16;
typedef unsigned int   u32;

#define DT_BF16 1
#define DT_F32  2

template<typename T> struct dtid;
template<> struct dtid<float> { static constexpr int v = DT_F32;  };
template<> struct dtid<u16>   { static constexpr int v = DT_BF16; };

typedef __attribute__((ext_vector_type(8))) short short8;   // 8 x bf16
typedef __attribute__((ext_vector_type(4))) float f32x4;
typedef __attribute__((ext_vector_type(4))) u32   u32x4;

__device__ __forceinline__ float u2f(u16 u) {
    union { u32 i; float f; } v; v.i = ((u32)u) << 16; return v.f;
}
__device__ __forceinline__ u16 f2bf(float f) {
    union { float f; u32 i; } v; v.f = f;
    u32 x = v.i;
    return (u16)((x + 0x7fffu + ((x >> 16) & 1u)) >> 16);   // RNE
}
__device__ __forceinline__ u32 pack2(float lo, float hi) {
    return (u32)f2bf(lo) | ((u32)f2bf(hi) << 16);
}

template<typename T> __device__ __forceinline__ float ldf(const T* p);
template<> __device__ __forceinline__ float ldf<float>(const float* p) { return *p; }
template<> __device__ __forceinline__ float ldf<u16>(const u16* p)     { return u2f(*p); }

template<typename T> __device__ __forceinline__ void stf(T* p, float v);
template<> __device__ __forceinline__ void stf<float>(float* p, float v) { *p = v; }
template<> __device__ __forceinline__ void stf<u16>(u16* p, float v)     { *p = f2bf(v); }

template<typename T> __device__ __forceinline__ float4 ld4(const T* p);
template<> __device__ __forceinline__ float4 ld4<float>(const float* p) {
    return *(const float4*)p;
}
template<> __device__ __forceinline__ float4 ld4<u16>(const u16* p) {
    ushort4 q = *(const ushort4*)p;
    return make_float4(u2f(q.x), u2f(q.y), u2f(q.z), u2f(q.w));
}

// async global->LDS, 16B per lane, linear dest (wave base + lane*16)
#define STG(g, l) __builtin_amdgcn_global_load_lds( \
    (const __attribute__((address_space(1))) unsigned int*)(const void*)(g), \
    (__attribute__((address_space(3))) unsigned int*)(void*)(l), 16, 0, 0)

// ---------------------------------------------------------------- dtype detect
__global__ void detect_kernel(const u32* __restrict__ fcos_words,
                              int* __restrict__ flag)
{
    *flag = (fcos_words[0] == 0x3F800000u) ? DT_F32 : DT_BF16;
}

__global__ void init_kernel(int* __restrict__ counts)   // counts[16]+cursor[16]
{
    if (threadIdx.x < 32) counts[threadIdx.x] = 0;
}

// ------------------------------------------------- RMSNorm: IT in -> fp32 out
template<typename IT, typename WT>
__global__ __launch_bounds__(256) void rmsnorm_kernel(const int* __restrict__ flag,
                                                      const IT* __restrict__ xin,
                                                      const WT* __restrict__ w,
                                                      float* __restrict__ out)
{
    if (*flag != dtid<WT>::v) return;
    int t = blockIdx.x;
    const IT* xb = xin + (size_t)t * DIM_;
    float ss = 0.f;
    for (int d = threadIdx.x; d < DIM_; d += 256) {
        float v = ldf(xb + d);
        ss += v * v;
    }
    #pragma unroll
    for (int o = 32; o > 0; o >>= 1) ss += __shfl_xor(ss, o);
    __shared__ float red[4];
    if ((threadIdx.x & 63) == 0) red[threadIdx.x >> 6] = ss;
    __syncthreads();
    float tot = red[0] + red[1] + red[2] + red[3];
    float inv = rsqrtf(tot * (1.0f / DIM_) + 1e-6f);
    for (int d = threadIdx.x; d < DIM_; d += 256)
        out[(size_t)t * DIM_ + d] = ldf(xb + d) * inv * ldf(w + d);
}

// ---------------------- GEMM: A(fp32 ws) @ B(T) -> CF(fp32) [+resid(T)]
template<typename T>
__global__ __launch_bounds__(256) void gemm_kernel(const int* __restrict__ flag,
                                                   const float* __restrict__ A,
                                                   const T* __restrict__ Bw,
                                                   float* __restrict__ CF,
                                                   const T* __restrict__ resid,
                                                   int M, int N, int K)
{
    if (*flag != dtid<T>::v) return;
    __shared__ float As[16][132];
    __shared__ float Bs[16][132];
    int t  = threadIdx.x;
    int bm = blockIdx.y, bn = blockIdx.x;

    int ar = t >> 2;             // A row within tile: 0..63 (and +64)
    int ak = (t & 3) << 2;       // A k-offset: 0,4,8,12
    int bkr = t >> 4;            // B k-row: 0..15
    int bc  = (t & 15) << 3;     // B col-offset: 0..120

    const float* Ap0 = A + (size_t)(bm * 128 + ar) * K + ak;
    const float* Ap1 = Ap0 + (size_t)64 * K;
    const T*     Bp  = Bw + (size_t)bkr * N + bn * 128 + bc;

    int lane = t & 63, w = t >> 6;
    int mi = ((lane & 7) + ((w & 1) << 3)) << 3;   // 0..120
    int ni = ((lane >> 3) + ((w >> 1) << 3)) << 3; // 0..120

    float acc[8][8] = {};

    float4 pa0 = *(const float4*)(Ap0);
    float4 pa1 = *(const float4*)(Ap1);
    float4 pb0 = ld4(Bp);
    float4 pb1 = ld4(Bp + 4);

    for (int k0 = 0; k0 < K; k0 += 16) {
        As[ak + 0][ar]      = pa0.x; As[ak + 1][ar]      = pa0.y;
        As[ak + 2][ar]      = pa0.z; As[ak + 3][ar]      = pa0.w;
        As[ak + 0][ar + 64] = pa1.x; As[ak + 1][ar + 64] = pa1.y;
        As[ak + 2][ar + 64] = pa1.z; As[ak + 3][ar + 64] = pa1.w;
        *(float4*)&Bs[bkr][bc]     = pb0;
        *(float4*)&Bs[bkr][bc + 4] = pb1;
        __syncthreads();

        if (k0 + 16 < K) {
            pa0 = *(const float4*)(Ap0 + k0 + 16);
            pa1 = *(const float4*)(Ap1 + k0 + 16);
            pb0 = ld4(Bp + (size_t)(k0 + 16) * N);
            pb1 = ld4(Bp + (size_t)(k0 + 16) * N + 4);
        }

        #pragma unroll
        for (int kk = 0; kk < 16; ++kk) {
            float4 a0 = *(const float4*)&As[kk][mi];
            float4 a1 = *(const float4*)&As[kk][mi + 4];
            float4 b0 = *(const float4*)&Bs[kk][ni];
            float4 b1 = *(const float4*)&Bs[kk][ni + 4];
            float a[8] = { a0.x, a0.y, a0.z, a0.w, a1.x, a1.y, a1.z, a1.w };
            float b[8] = { b0.x, b0.y, b0.z, b0.w, b1.x, b1.y, b1.z, b1.w };
            #pragma unroll
            for (int i = 0; i < 8; ++i)
                #pragma unroll
                for (int j = 0; j < 8; ++j) acc[i][j] += a[i] * b[j];
        }
        __syncthreads();
    }

    #pragma unroll
    for (int i = 0; i < 8; ++i) {
        size_t off = (size_t)(bm * 128 + mi + i) * N + bn * 128 + ni;
        #pragma unroll
        for (int j = 0; j < 8; ++j) {
            float c = acc[i][j];
            if (resid) c += ldf(resid + off + j);
            CF[off + j] = c;
        }
    }
}

// ---------------------------------------------------------------- RoPE (fp32, in place)
template<typename FT>
__global__ __launch_bounds__(256) void rope_kernel(const int* __restrict__ flag,
                                                   float* __restrict__ t,
                                                   const FT* __restrict__ fc,
                                                   const FT* __restrict__ fs,
                                                   int nheads, int npairs)
{
    if (*flag != dtid<FT>::v) return;
    int gid = blockIdx.x * 256 + threadIdx.x;
    if (gid >= npairs) return;
    int i    = gid & 63;
    int rest = gid >> 6;
    int h    = rest % nheads;
    int tok  = rest / nheads;
    int spos = tok & (S_ - 1);
    float c = ldf(fc + spos * 64 + i);
    float s = ldf(fs + spos * 64 + i);
    size_t base = ((size_t)tok * nheads + h) * HD_ + 2 * i;
    float t1 = t[base], t2 = t[base + 1];
    t[base]     = t1 * c - t2 * s;
    t[base + 1] = t1 * s + t2 * c;
}

// ---------------------------------------------------------------- fp32 -> bf16 casts
__global__ __launch_bounds__(256) void cast_kernel(const int* __restrict__ flag,
                                                   const float* __restrict__ src,
                                                   u16* __restrict__ dst, int n)
{
    if (*flag != DT_BF16) return;
    int i = blockIdx.x * 256 + threadIdx.x;
    if (i < n) dst[i] = f2bf(src[i]);
}

// h2 fp32 -> bf16 (fp32 mode), 8 elems/thread
__global__ __launch_bounds__(256) void cast_h2_kernel(const int* __restrict__ flag,
                                                      const float* __restrict__ src,
                                                      u16* __restrict__ dst, int n)
{
    if (*flag != DT_F32) return;
    int i = (blockIdx.x * 256 + threadIdx.x) * 8;
    if (i >= n) return;
    float4 a = *(const float4*)&src[i];
    float4 b = *(const float4*)&src[i + 4];
    short8 o;
    o[0] = (short)f2bf(a.x); o[1] = (short)f2bf(a.y);
    o[2] = (short)f2bf(a.z); o[3] = (short)f2bf(a.w);
    o[4] = (short)f2bf(b.x); o[5] = (short)f2bf(b.y);
    o[6] = (short)f2bf(b.z); o[7] = (short)f2bf(b.w);
    *(short8*)&dst[i] = o;
}

// ------------------- weight transpose+convert: src fp32 [K][N] -> dst bf16 [N][K]
// tile 64x64, grid (N/64, K/64, experts)
__global__ __launch_bounds__(256) void wtrans_kernel(const int* __restrict__ flag,
                                                     const float* __restrict__ src,
                                                     u16* __restrict__ dst,
                                                     int K, int N)
{
    if (*flag != DT_F32) return;
    size_t zoff = (size_t)blockIdx.z * K * N;
    src += zoff; dst += zoff;
    int n0 = blockIdx.x * 64, k0 = blockIdx.y * 64;
    __shared__ u16 tl[64][72];
    int t  = threadIdx.x;
    int kr = t >> 2;             // 0..63
    int c4 = (t & 3) * 16;       // 0,16,32,48
    #pragma unroll
    for (int i = 0; i < 4; ++i) {
        float4 f = *(const float4*)&src[(size_t)(k0 + kr) * N + n0 + c4 + i * 4];
        *(u32*)&tl[kr][c4 + i * 4 + 0] = pack2(f.x, f.y);
        *(u32*)&tl[kr][c4 + i * 4 + 2] = pack2(f.z, f.w);
    }
    __syncthreads();
    int nr = t >> 2;
    int kc = (t & 3) * 16;
    short8 o0, o1;
    #pragma unroll
    for (int i = 0; i < 8; ++i) {
        o0[i] = (short)tl[kc + i][nr];
        o1[i] = (short)tl[kc + 8 + i][nr];
    }
    *(short8*)&dst[(size_t)(n0 + nr) * K + k0 + kc]     = o0;
    *(short8*)&dst[(size_t)(n0 + nr) * K + k0 + kc + 8] = o1;
}

// --------------------------- Flash attention, split-bf16 MFMA (fp32-accurate)
__global__ __launch_bounds__(256) void attn_mfma_kernel(const int* __restrict__ flag,
                                                        int want,
                                                        float* __restrict__ q,
                                                        const float* __restrict__ k,
                                                        const float* __restrict__ v)
{
    if (*flag != want) return;
    int qt = blockIdx.x;          // 0..31 (query tile of 64)
    int h  = blockIdx.y;          // 0..15
    int b  = blockIdx.z;          // 0..1
    int kvh = h >> 2;
    int t = threadIdx.x;
    int wv = t >> 6, lane = t & 63;
    int qf = lane >> 4, l16 = lane & 15;

    __shared__ u16 Khi[32 * 128];         // [j][d] bf16 hi, 256B rows, XOR-swizzled
    __shared__ u16 Klo[32 * 128];
    __shared__ u16 Vthi[128 * 40];        // [d][j] bf16 hi, pitch 40
    __shared__ u16 Vtlo[128 * 40];
    __shared__ u32 Plds[4][16 * 36];      // per-wave P bounce: [q][j] packed hi|lo

    int q0   = qt * 64;
    int qrow = q0 + wv * 16 + l16;        // this lane's query (softmax column)
    const float* kb = k + (size_t)b * S_ * (NKV_ * HD_) + kvh * HD_;
    const float* vb = v + (size_t)b * S_ * (NKV_ * HD_) + kvh * HD_;

    size_t qbase = ((size_t)(b * S_ + qrow) * NH_ + h) * HD_;
    short8 qhi[4], qlo[4];
    #pragma unroll
    for (int c = 0; c < 4; ++c) {
        const float* qp = q + qbase + c * 32 + qf * 8;
        float4 f0 = *(const float4*)qp;
        float4 f1 = *(const float4*)(qp + 4);
        float xs[8] = { f0.x, f0.y, f0.z, f0.w, f1.x, f1.y, f1.z, f1.w };
        #pragma unroll
        for (int u = 0; u < 8; ++u) {
            u16 hh = f2bf(xs[u]);
            qhi[c][u] = (short)hh;
            qlo[c][u] = (short)f2bf(xs[u] - u2f(hh));
        }
    }

    f32x4 Ot[8];                          // O^T[d = dt*16+qf*4+r][q = l16]
    #pragma unroll
    for (int dt = 0; dt < 8; ++dt) Ot[dt] = (f32x4){0.f, 0.f, 0.f, 0.f};
    float m = -1e30f, l = 0.f;
    const float scale = 0.08838834764831845f;

    int sj  = t >> 3;                     // K: row 0..31
    int sa  = t & 7;                      // K: d-group 0..7 (16 floats each)
    int vjp = t & 15;                     // V: j-pair 0..15
    int vdg = t >> 4;                     // V: d-group 0..15 (8 floats each)

    int ntiles = (q0 + 64) >> 5;          // qt*2 + 2
    for (int tile = 0; tile < ntiles; ++tile) {
        int jt0 = tile << 5;
        __syncthreads();
        {
            const float* krow = kb + (size_t)(jt0 + sj) * (NKV_ * HD_);
            #pragma unroll
            for (int i = 0; i < 4; ++i) {
                int d = sa * 16 + i * 4;
                float4 f = *(const float4*)(krow + d);
                ushort4 hi, lo;
                hi.x = f2bf(f.x); lo.x = f2bf(f.x - u2f(hi.x));
                hi.y = f2bf(f.y); lo.y = f2bf(f.y - u2f(hi.y));
                hi.z = f2bf(f.z); lo.z = f2bf(f.z - u2f(hi.z));
                hi.w = f2bf(f.w); lo.w = f2bf(f.w - u2f(hi.w));
                int bix = (d * 2) ^ ((sj & 7) << 4);
                *(ushort4*)&Khi[sj * 128 + (bix >> 1)] = hi;
                *(ushort4*)&Klo[sj * 128 + (bix >> 1)] = lo;
            }
        }
        {
            #pragma unroll
            for (int p = 0; p < 2; ++p) {
                int d = vdg * 8 + p * 4;
                const float* v0 = vb + (size_t)(jt0 + 2 * vjp) * (NKV_ * HD_) + d;
                const float* v1 = v0 + NKV_ * HD_;
                float4 a = *(const float4*)v0;
                float4 c4 = *(const float4*)v1;
                float aa[4] = { a.x, a.y, a.z, a.w };
                float bb[4] = { c4.x, c4.y, c4.z, c4.w };
                #pragma unroll
                for (int i = 0; i < 4; ++i) {
                    int r = d + i;
                    u16 h0 = f2bf(aa[i]); u16 l0 = f2bf(aa[i] - u2f(h0));
                    u16 h1 = f2bf(bb[i]); u16 l1 = f2bf(bb[i] - u2f(h1));
                    *(u32*)&Vthi[r * 40 + vjp * 2] = (u32)h0 | ((u32)h1 << 16);
                    *(u32*)&Vtlo[r * 40 + vjp * 2] = (u32)l0 | ((u32)l1 << 16);
                }
            }
        }
        __syncthreads();

        f32x4 st[2];
        st[0] = (f32x4){0.f, 0.f, 0.f, 0.f};
        st[1] = (f32x4){0.f, 0.f, 0.f, 0.f};
        #pragma unroll
        for (int jt2 = 0; jt2 < 2; ++jt2) {
            int row = jt2 * 16 + l16;
            #pragma unroll
            for (int c = 0; c < 4; ++c) {
                int bix = (c * 64 + qf * 16) ^ ((l16 & 7) << 4);
                short8 khi = *(const short8*)&Khi[row * 128 + (bix >> 1)];
                short8 klo = *(const short8*)&Klo[row * 128 + (bix >> 1)];
                st[jt2] = __builtin_amdgcn_mfma_f32_16x16x32_bf16(khi, qhi[c], st[jt2], 0, 0, 0);
                st[jt2] = __builtin_amdgcn_mfma_f32_16x16x32_bf16(khi, qlo[c], st[jt2], 0, 0, 0);
                st[jt2] = __builtin_amdgcn_mfma_f32_16x16x32_bf16(klo, qhi[c], st[jt2], 0, 0, 0);
            }
        }

        float pv[8];
        float pmax = -1e30f;
        #pragma unroll
        for (int jt2 = 0; jt2 < 2; ++jt2) {
            #pragma unroll
            for (int r = 0; r < 4; ++r) {
                int j = jt0 + jt2 * 16 + qf * 4 + r;
                float s = st[jt2][r] * scale;
                if (j > qrow) s = -1e30f;
                pv[jt2 * 4 + r] = s;
                pmax = fmaxf(pmax, s);
            }
        }
        pmax = fmaxf(pmax, __shfl_xor(pmax, 16));
        pmax = fmaxf(pmax, __shfl_xor(pmax, 32));
        float mn    = fmaxf(m, pmax);
        float alpha = __expf(m - mn);
        m = mn;
        float rs = 0.f;
        u32 pw[8];
        #pragma unroll
        for (int i = 0; i < 8; ++i) {
            float p = __expf(pv[i] - mn);
            rs += p;
            u16 ph = f2bf(p);
            pw[i] = (u32)ph | ((u32)f2bf(p - u2f(ph)) << 16);
        }
        rs += __shfl_xor(rs, 16);
        rs += __shfl_xor(rs, 32);
        l = l * alpha + rs;

        u32* pl = &Plds[wv][l16 * 36];
        *(u32x4*)&pl[qf * 4]      = (u32x4){ pw[0], pw[1], pw[2], pw[3] };
        *(u32x4*)&pl[16 + qf * 4] = (u32x4){ pw[4], pw[5], pw[6], pw[7] };
        asm volatile("s_waitcnt lgkmcnt(0)" ::: "memory");
        __builtin_amdgcn_sched_barrier(0);
        u32x4 w0 = *(const u32x4*)&Plds[wv][l16 * 36 + qf * 8];
        u32x4 w1 = *(const u32x4*)&Plds[wv][l16 * 36 + qf * 8 + 4];
        short8 phi, plo;
        #pragma unroll
        for (int u = 0; u < 4; ++u) {
            phi[u]     = (short)(w0[u] & 0xffffu); plo[u]     = (short)(w0[u] >> 16);
            phi[4 + u] = (short)(w1[u] & 0xffffu); plo[4 + u] = (short)(w1[u] >> 16);
        }

        #pragma unroll
        for (int dt = 0; dt < 8; ++dt) {
            #pragma unroll
            for (int r = 0; r < 4; ++r) Ot[dt][r] *= alpha;
        }
        #pragma unroll
        for (int dt = 0; dt < 8; ++dt) {
            int row = dt * 16 + l16;
            short8 vhi = *(const short8*)&Vthi[row * 40 + qf * 8];
            short8 vlo = *(const short8*)&Vtlo[row * 40 + qf * 8];
            Ot[dt] = __builtin_amdgcn_mfma_f32_16x16x32_bf16(vhi, phi, Ot[dt], 0, 0, 0);
            Ot[dt] = __builtin_amdgcn_mfma_f32_16x16x32_bf16(vhi, plo, Ot[dt], 0, 0, 0);
            Ot[dt] = __builtin_amdgcn_mfma_f32_16x16x32_bf16(vlo, phi, Ot[dt], 0, 0, 0);
        }
    }

    float invl = 1.f / l;
    #pragma unroll
    for (int dt = 0; dt < 8; ++dt) {
        #pragma unroll
        for (int r = 0; r < 4; ++r)
            q[qbase + dt * 16 + qf * 4 + r] = Ot[dt][r] * invl;
    }
}

// ---------------------------------------------------------------- top-2 gate
template<typename T>
__global__ __launch_bounds__(64) void gate_kernel(const int* __restrict__ flag,
                                                  const float* __restrict__ xt,
                                                  const T* __restrict__ gw,
                                                  int* __restrict__ eidx,
                                                  float* __restrict__ egw,
                                                  int* __restrict__ counts)
{
    if (*flag != dtid<T>::v) return;
    int t = blockIdx.x, lane = threadIdx.x;
    float acc[NE_] = {};
    const float* xr = xt + (size_t)t * DIM_;
    for (int d = lane; d < DIM_; d += 64) {
        float xd = xr[d];
        #pragma unroll
        for (int e = 0; e < NE_; ++e) acc[e] += xd * ldf(gw + d * NE_ + e);
    }
    #pragma unroll
    for (int e = 0; e < NE_; ++e)
        #pragma unroll
        for (int off = 32; off > 0; off >>= 1) acc[e] += __shfl_xor(acc[e], off);
    if (lane == 0) {
        int i0 = 0; float m0 = acc[0];
        #pragma unroll
        for (int e = 1; e < NE_; ++e) if (acc[e] > m0) { m0 = acc[e]; i0 = e; }
        int i1 = (i0 == 0) ? 1 : 0; float m1 = acc[i1];
        for (int e = i1 + 1; e < NE_; ++e)
            if (e != i0 && acc[e] > m1) { m1 = acc[e]; i1 = e; }
        float e1  = __expf(m1 - m0);
        float inv = 1.f / (1.f + e1);
        eidx[t * 2] = i0; eidx[t * 2 + 1] = i1;
        egw [t * 2] = inv; egw [t * 2 + 1] = e1 * inv;
        atomicAdd(&counts[i0], 1);
        atomicAdd(&counts[i1], 1);
    }
}

__global__ void offs_kernel(const int* __restrict__ counts, int* __restrict__ offs)
{
    if (threadIdx.x == 0) {
        int off = 0;
        for (int e = 0; e < NE_; ++e) { offs[e] = off; off += counts[e]; }
    }
}

__global__ __launch_bounds__(256) void scatter_kernel(const int* __restrict__ eidx,
                                                      const int* __restrict__ offs,
                                                      int* __restrict__ cursor,
                                                      int* __restrict__ list)
{
    int s = blockIdx.x * 256 + threadIdx.x;
    if (s >= T_ * 2) return;
    int e = eidx[s] & 7;
    int pos = atomicAdd(&cursor[e], 1);
    list[offs[e] + pos] = s;
}

// ------------------- MoE phase A v2: he = silu(X@W1)*(X@W3), bf16 MFMA GEMM
// Block 64 tokens x 128 n; 4 waves each 64x32. BK=64, double-buffered
// global_load_lds with source-chunk XOR swizzle (chunk ^= row&7).
__global__ __launch_bounds__(256) void moe_h2_kernel(const int* __restrict__ flag,
                                                     const u16* __restrict__ h2bf,
                                                     const u16* __restrict__ w1t,
                                                     const u16* __restrict__ w3t,
                                                     const u16* __restrict__ sw1t,
                                                     const u16* __restrict__ sw3t,
                                                     const int* __restrict__ list,
                                                     const int* __restrict__ counts,
                                                     const int* __restrict__ offs,
                                                     u16* __restrict__ he)
{
    if (*flag != DT_F32) return;
    int e   = blockIdx.z;
    int cnt = (e < 8) ? counts[e] : T_;
    int my0 = blockIdx.y * 64;
    if (my0 >= cnt) return;
    int n0   = blockIdx.x * 128;
    int base = ((e < 8) ? offs[e] : 2 * T_) + my0;
    const u16* W1 = (e < 8) ? w1t + (size_t)e * HID_ * DIM_ : sw1t;
    const u16* W3 = (e < 8) ? w3t + (size_t)e * HID_ * DIM_ : sw3t;

    __shared__ __align__(16) u16 Asb[2][64 * 64];       // [m][k] 128B rows
    __shared__ __align__(16) u16 Bsb[2][2][128 * 64];   // [mat][n][k]
    __shared__ int toks[64];

    int t = threadIdx.x;
    if (t < 64) {
        int mm = (my0 + t < cnt) ? my0 + t : cnt - 1;
        toks[t] = (e < 8) ? (list[offs[e] + mm] >> 1) : mm;
    }
    __syncthreads();

    int w = t >> 6, lane = t & 63;
    int q = lane >> 4, l16 = lane & 15;
    int lr = lane >> 3, lc = lane & 7;
    int sx = (lc ^ lr) * 8;              // pre-swizzled source chunk (u16 elems)

    const u16* asrc0 = h2bf + (size_t)toks[w * 16 + lr] * DIM_ + sx;
    const u16* asrc1 = h2bf + (size_t)toks[w * 16 + 8 + lr] * DIM_ + sx;
    const u16* b1s0 = W1 + (size_t)(n0 + w * 32 +  0 + lr) * DIM_ + sx;
    const u16* b1s1 = W1 + (size_t)(n0 + w * 32 +  8 + lr) * DIM_ + sx;
    const u16* b1s2 = W1 + (size_t)(n0 + w * 32 + 16 + lr) * DIM_ + sx;
    const u16* b1s3 = W1 + (size_t)(n0 + w * 32 + 24 + lr) * DIM_ + sx;
    const u16* b3s0 = W3 + (size_t)(n0 + w * 32 +  0 + lr) * DIM_ + sx;
    const u16* b3s1 = W3 + (size_t)(n0 + w * 32 +  8 + lr) * DIM_ + sx;
    const u16* b3s2 = W3 + (size_t)(n0 + w * 32 + 16 + lr) * DIM_ + sx;
    const u16* b3s3 = W3 + (size_t)(n0 + w * 32 + 24 + lr) * DIM_ + sx;

    #define STAGE_H(bf, k0) do {                                        \
        STG(asrc0 + (k0), &Asb[bf][(w * 16) * 64]);                     \
        STG(asrc1 + (k0), &Asb[bf][(w * 16 + 8) * 64]);                 \
        STG(b1s0 + (k0), &Bsb[bf][0][(w * 32) * 64]);                   \
        STG(b1s1 + (k0), &Bsb[bf][0][(w * 32 + 8) * 64]);               \
        STG(b1s2 + (k0), &Bsb[bf][0][(w * 32 + 16) * 64]);              \
        STG(b1s3 + (k0), &Bsb[bf][0][(w * 32 + 24) * 64]);              \
        STG(b3s0 + (k0), &Bsb[bf][1][(w * 32) * 64]);                   \
        STG(b3s1 + (k0), &Bsb[bf][1][(w * 32 + 8) * 64]);               \
        STG(b3s2 + (k0), &Bsb[bf][1][(w * 32 + 16) * 64]);              \
        STG(b3s3 + (k0), &Bsb[bf][1][(w * 32 + 24) * 64]);              \
    } while (0)

    f32x4 acc1[4][2], acc3[4][2];
    #pragma unroll
    for (int mt = 0; mt < 4; ++mt)
        #pragma unroll
        for (int nt = 0; nt < 2; ++nt) {
            acc1[mt][nt] = (f32x4){0.f, 0.f, 0.f, 0.f};
            acc3[mt][nt] = (f32x4){0.f, 0.f, 0.f, 0.f};
        }

    const int NK = DIM_ / 64;            // 32
    STAGE_H(0, 0);
    asm volatile("s_waitcnt vmcnt(0)" ::: "memory");
    __syncthreads();
    for (int ks = 0; ks < NK; ++ks) {
        int cur = ks & 1;
        if (ks + 1 < NK) {
            if (cur) STAGE_H(0, (ks + 1) * 64); else STAGE_H(1, (ks + 1) * 64);
        }
        #pragma unroll
        for (int ksub = 0; ksub < 2; ++ksub) {
            int ch = (((ksub << 2) + q) ^ (l16 & 7)) * 8;
            short8 af[4];
            #pragma unroll
            for (int mt = 0; mt < 4; ++mt)
                af[mt] = *(const short8*)&Asb[cur][(mt * 16 + l16) * 64 + ch];
            #pragma unroll
            for (int nt = 0; nt < 2; ++nt) {
                int boff = (w * 32 + nt * 16 + l16) * 64 + ch;
                short8 b1 = *(const short8*)&Bsb[cur][0][boff];
                short8 b3 = *(const short8*)&Bsb[cur][1][boff];
                #pragma unroll
                for (int mt = 0; mt < 4; ++mt) {
                    acc1[mt][nt] = __builtin_amdgcn_mfma_f32_16x16x32_bf16(af[mt], b1, acc1[mt][nt], 0, 0, 0);
                    acc3[mt][nt] = __builtin_amdgcn_mfma_f32_16x16x32_bf16(af[mt], b3, acc3[mt][nt], 0, 0, 0);
                }
            }
        }
        asm volatile("s_waitcnt vmcnt(0)" ::: "memory");
        __syncthreads();
    }
    #undef STAGE_H

    #pragma unroll
    for (int mt = 0; mt < 4; ++mt)
        #pragma unroll
        for (int nt = 0; nt < 2; ++nt)
            #pragma unroll
            for (int r = 0; r < 4; ++r) {
                int m = mt * 16 + q * 4 + r;
                if (my0 + m < cnt) {
                    float h1 = acc1[mt][nt][r], h3 = acc3[mt][nt][r];
                    float vv = (h1 / (1.f + __expf(-h1))) * h3;
                    he[(size_t)(base + m) * HID_ + n0 + w * 32 + nt * 16 + l16] = f2bf(vv);
                }
            }
}

// ------------------- MoE phase B v2: out += g * (he @ W2), bf16 MFMA + atomics
__global__ __launch_bounds__(256) void moe_y2_kernel(const int* __restrict__ flag,
                                                     const u16* __restrict__ he,
                                                     const u16* __restrict__ w2t,
                                                     const u16* __restrict__ sw2t,
                                                     const int* __restrict__ list,
                                                     const int* __restrict__ counts,
                                                     const int* __restrict__ offs,
                                                     const float* __restrict__ egw,
                                                     float* __restrict__ out)
{
    if (*flag != DT_F32) return;
    int e   = blockIdx.z;
    int cnt = (e < 8) ? counts[e] : T_;
    int my0 = blockIdx.y * 64;
    if (my0 >= cnt) return;
    int d0   = blockIdx.x * 128;
    int base = ((e < 8) ? offs[e] : 2 * T_) + my0;
    const u16* W2 = (e < 8) ? w2t + (size_t)e * DIM_ * HID_ : sw2t;

    __shared__ __align__(16) u16 Asb[2][64 * 64];
    __shared__ __align__(16) u16 Bsb[2][128 * 64];
    __shared__ int   stok[64];
    __shared__ float sg[64];

    int t = threadIdx.x;
    if (t < 64) {
        int mm = (my0 + t < cnt) ? my0 + t : cnt - 1;
        if (e < 8) {
            int s = list[offs[e] + mm];
            stok[t] = s >> 1; sg[t] = egw[s];
        } else {
            stok[t] = mm; sg[t] = 1.f;
        }
    }
    __syncthreads();

    int w = t >> 6, lane = t & 63;
    int q = lane >> 4, l16 = lane & 15;
    int lr = lane >> 3, lc = lane & 7;
    int sx = (lc ^ lr) * 8;

    const u16* asrc0 = he + (size_t)(base + w * 16 + lr) * HID_ + sx;
    const u16* asrc1 = he + (size_t)(base + w * 16 + 8 + lr) * HID_ + sx;
    const u16* bs0 = W2 + (size_t)(d0 + w * 32 +  0 + lr) * HID_ + sx;
    const u16* bs1 = W2 + (size_t)(d0 + w * 32 +  8 + lr) * HID_ + sx;
    const u16* bs2 = W2 + (size_t)(d0 + w * 32 + 16 + lr) * HID_ + sx;
    const u16* bs3 = W2 + (size_t)(d0 + w * 32 + 24 + lr) * HID_ + sx;

    #define STAGE_Y(bf, k0) do {                                        \
        STG(asrc0 + (k0), &Asb[bf][(w * 16) * 64]);                     \
        STG(asrc1 + (k0), &Asb[bf][(w * 16 + 8) * 64]);                 \
        STG(bs0 + (k0), &Bsb[bf][(w * 32) * 64]);                       \
        STG(bs1 + (k0), &Bsb[bf][(w * 32 + 8) * 64]);                   \
        STG(bs2 + (k0), &Bsb[bf][(w * 32 + 16) * 64]);                  \
        STG(bs3 + (k0), &Bsb[bf][(w * 32 + 24) * 64]);                  \
    } while (0)

    f32x4 acc[4][2];
    #pragma unroll
    for (int mt = 0; mt < 4; ++mt)
        #pragma unroll
        for (int nt = 0; nt < 2; ++nt) acc[mt][nt] = (f32x4){0.f, 0.f, 0.f, 0.f};

    const int NK = HID_ / 64;            // 16
    STAGE_Y(0, 0);
    asm volatile("s_waitcnt vmcnt(0)" ::: "memory");
    __syncthreads();
    for (int ks = 0; ks < NK; ++ks) {
        int cur = ks & 1;
        if (ks + 1 < NK) {
            if (cur) STAGE_Y(0, (ks + 1) * 64); else STAGE_Y(1, (ks + 1) * 64);
        }
        #pragma unroll
        for (int ksub = 0; ksub < 2; ++ksub) {
            int ch = (((ksub << 2) + q) ^ (l16 & 7)) * 8;
            short8 af[4];
            #pragma unroll
            for (int mt = 0; mt < 4; ++mt)
                af[mt] = *(const short8*)&Asb[cur][(mt * 16 + l16) * 64 + ch];
            #pragma unroll
            for (int nt = 0; nt < 2; ++nt) {
                short8 bf_ = *(const short8*)&Bsb[cur][(w * 32 + nt * 16 + l16) * 64 + ch];
                #pragma unroll
                for (int mt = 0; mt < 4; ++mt)
                    acc[mt][nt] = __builtin_amdgcn_mfma_f32_16x16x32_bf16(af[mt], bf_, acc[mt][nt], 0, 0, 0);
            }
        }
        asm volatile("s_waitcnt vmcnt(0)" ::: "memory");
        __syncthreads();
    }
    #undef STAGE_Y

    #pragma unroll
    for (int mt = 0; mt < 4; ++mt)
        #pragma unroll
        for (int r = 0; r < 4; ++r) {
            int m = mt * 16 + q * 4 + r;
            if (my0 + m < cnt) {
                int   tok = stok[m];
                float g   = sg[m];
                float* orow = out + (size_t)tok * DIM_ + d0 + w * 32 + l16;
                unsafeAtomicAdd(orow,      g * acc[mt][0][r]);
                unsafeAtomicAdd(orow + 16, g * acc[mt][1][r]);
            }
        }
}

// --------------- old per-token MoE: bf16-external insurance path only
template<typename T>
__global__ __launch_bounds__(256) void moe_kernel(const int* __restrict__ flag,
                                                  const float* __restrict__ h2,
                                                  const float* __restrict__ x1,
                                                  const T* __restrict__ w1,
                                                  const T* __restrict__ w2,
                                                  const T* __restrict__ w3,
                                                  const T* __restrict__ sw1,
                                                  const T* __restrict__ sw2,
                                                  const T* __restrict__ sw3,
                                                  const int* __restrict__ eidx,
                                                  const float* __restrict__ egw,
                                                  T* __restrict__ out)
{
    if (*flag != dtid<T>::v) return;
    int t = blockIdx.x;
    int j = threadIdx.x;
    __shared__ float sx[DIM_];
    __shared__ float she[HID_];
    for (int d = j; d < DIM_; d += 256)
        sx[d] = h2[(size_t)t * DIM_ + d];
    __syncthreads();

    float y[8] = {};
    for (int pass = 0; pass < 3; ++pass) {
        const T *W1, *W2, *W3; float g;
        if (pass < 2) {
            int e = eidx[t * 2 + pass] & 7;
            g = egw[t * 2 + pass];
            W1 = w1 + (size_t)e * DIM_ * HID_;
            W3 = w3 + (size_t)e * DIM_ * HID_;
            W2 = w2 + (size_t)e * HID_ * DIM_;
        } else {
            W1 = sw1; W3 = sw3; W2 = sw2; g = 1.f;
        }
        float a1[4] = {}, a3[4] = {};
        for (int d = 0; d < DIM_; ++d) {
            float xd = sx[d];
            const T* r1 = W1 + (size_t)d * HID_;
            const T* r3 = W3 + (size_t)d * HID_;
            #pragma unroll
            for (int i = 0; i < 4; ++i) {
                a1[i] += xd * ldf(r1 + j + 256 * i);
                a3[i] += xd * ldf(r3 + j + 256 * i);
            }
        }
        #pragma unroll
        for (int i = 0; i < 4; ++i) {
            float h1 = a1[i];
            she[j + 256 * i] = g * (h1 / (1.f + __expf(-h1))) * a3[i];
        }
        __syncthreads();
        for (int hh = 0; hh < HID_; ++hh) {
            float hv = she[hh];
            const T* r2 = W2 + (size_t)hh * DIM_;
            #pragma unroll
            for (int i = 0; i < 8; ++i) y[i] += hv * ldf(r2 + j + 256 * i);
        }
        __syncthreads();
    }
    #pragma unroll
    for (int i = 0; i < 8; ++i) {
        size_t idx = (size_t)t * DIM_ + j + 256 * i;
        stf(out + idx, y[i] + x1[idx]);
    }
}

// ================================================================ launch
extern "C" void kernel_launch(void* const* d_in, const int* in_sizes, int n_in,
                              void* d_out, int out_size, void* d_ws, size_t ws_size,
                              hipStream_t stream)
{
    const size_t TD  = (size_t)T_ * DIM_;            // 8.4M elems
    const size_t TKV = (size_t)T_ * NKV_ * HD_;      // 2.1M elems

    char* ws = (char*)d_ws;
    int*   flag   = (int*)ws;   ws += 16;
    int*   counts = (int*)ws;   ws += 16 * 4;        // counts[16]
    int*   cursor = counts + 16;
    ws += 16 * 4;                                    // cursor[16]
    int*   offs   = (int*)ws;   ws += 16 * 4;
    int*   eidx   = (int*)ws;   ws += (size_t)T_ * 2 * 4;
    float* egw    = (float*)ws; ws += (size_t)T_ * 2 * 4;
    int*   list   = (int*)ws;   ws += (size_t)T_ * 2 * 4;
    float* bufA   = (float*)ws; ws += TD * 4;        // h, h2, then w1t/w2t
    float* bufB   = (float*)ws; ws += TD * 4;        // q/attn-out; he + sw1t/sw3t
    u16*   he     = (u16*)bufB;                      // 12288*1024 bf16 = 25.2MB
    float* bufKV  = (float*)ws; ws += 2 * TKV * 4;   // bf16-mode KV; fp32: h2bf/sw2t
    float* bufX1f = (float*)ws; ws += TD * 4;        // bf16-mode x1; fp32: w3t

    detect_kernel<<<1, 1, 0, stream>>>((const u32*)d_in[1], flag);
    init_kernel<<<1, 64, 0, stream>>>(counts);

    dim3 gq(DIM_ / 128, T_ / 128);
    dim3 gkv((NKV_ * HD_) / 128, T_ / 128);
    dim3 gattn(S_ / 64, NH_, B_);
    int qpairs = T_ * NH_ * (HD_ / 2);
    int kpairs = T_ * NKV_ * (HD_ / 2);

    #define FOR_DTYPE(T)                                                          \
    {                                                                             \
        const T* x      = (const T*)d_in[0];                                      \
        const T* fcos   = (const T*)d_in[1];                                      \
        const T* fsin   = (const T*)d_in[2];                                      \
        const T* attn_w = (const T*)d_in[3];                                      \
        const T* ffn_w  = (const T*)d_in[4];                                      \
        const T* wq     = (const T*)d_in[5];                                      \
        const T* wk     = (const T*)d_in[6];                                      \
        const T* wv     = (const T*)d_in[7];                                      \
        const T* wo     = (const T*)d_in[8];                                      \
        const T* gate_w = (const T*)d_in[9];                                      \
        T* out_x = (T*)d_out;                                                     \
        T* out_k = out_x + TD;                                                    \
        T* out_v = out_k + TKV;                                                   \
        const bool isF32 = (dtid<T>::v == DT_F32);                                \
        float* kf  = isF32 ? (float*)out_k : bufKV;                               \
        float* vf  = isF32 ? (float*)out_v : bufKV + TKV;                         \
        float* x1f = isF32 ? (float*)out_x : bufX1f;                              \
        rmsnorm_kernel<T, T><<<T_, 256, 0, stream>>>(flag, x, attn_w, bufA);      \
        gemm_kernel<T><<<gq,  256, 0, stream>>>(flag, bufA, wq, bufB,             \
                                                (const T*)nullptr, T_, DIM_, DIM_);\
        gemm_kernel<T><<<gkv, 256, 0, stream>>>(flag, bufA, wk, kf,               \
                                                (const T*)nullptr,                \
                                                T_, NKV_ * HD_, DIM_);            \
        gemm_kernel<T><<<gkv, 256, 0, stream>>>(flag, bufA, wv, vf,               \
                                                (const T*)nullptr,                \
                                                T_, NKV_ * HD_, DIM_);            \
        rope_kernel<T><<<(qpairs + 255) / 256, 256, 0, stream>>>(                 \
            flag, bufB, fcos, fsin, NH_, qpairs);                                 \
        rope_kernel<T><<<(kpairs + 255) / 256, 256, 0, stream>>>(                 \
            flag, kf, fcos, fsin, NKV_, kpairs);                                  \
        if (!isF32) {                                                             \
            cast_kernel<<<(int)((TKV + 255) / 256), 256, 0, stream>>>(            \
                flag, kf, (u16*)out_k, (int)TKV);                                 \
            cast_kernel<<<(int)((TKV + 255) / 256), 256, 0, stream>>>(            \
                flag, vf, (u16*)out_v, (int)TKV);                                 \
        }                                                                         \
        attn_mfma_kernel<<<gattn, 256, 0, stream>>>(flag, dtid<T>::v,             \
                                                    bufB, kf, vf);                \
        gemm_kernel<T><<<gq, 256, 0, stream>>>(flag, bufB, wo, x1f, x,            \
                                               T_, DIM_, DIM_);                   \
        rmsnorm_kernel<float, T><<<T_, 256, 0, stream>>>(flag, x1f, ffn_w, bufA); \
        gate_kernel<T><<<T_, 64, 0, stream>>>(flag, bufA, gate_w, eidx, egw,      \
                                              counts);                            \
    }

    FOR_DTYPE(float)
    FOR_DTYPE(u16)
    #undef FOR_DTYPE

    offs_kernel<<<1, 1, 0, stream>>>(counts, offs);
    scatter_kernel<<<(T_ * 2 + 255) / 256, 256, 0, stream>>>(eidx, offs, cursor, list);

    // fp32 path: pre-transpose weights to bf16 [n][k], then MFMA MoE
    {
        const float* w1  = (const float*)d_in[10];
        const float* w2  = (const float*)d_in[11];
        const float* w3  = (const float*)d_in[12];
        const float* sw1 = (const float*)d_in[13];
        const float* sw2 = (const float*)d_in[14];
        const float* sw3 = (const float*)d_in[15];

        u16* w1t  = (u16*)bufA;                       // 32MB (h2 dead after cast)
        u16* w3t  = (u16*)bufX1f;                     // 32MB (unused in fp32 mode)
        u16* h2bf = (u16*)bufKV;                      // 16.8MB
        u16* sw1t = (u16*)((char*)bufB + (size_t)(3 * T_) * HID_ * 2);  // he end
        u16* sw3t = sw1t + (size_t)HID_ * DIM_;
        u16* w2t  = (u16*)bufA;                       // reuse after moe_h2
        u16* sw2t = (u16*)bufKV;                      // reuse after moe_h2

        cast_h2_kernel<<<(int)(TD / (256 * 8)), 256, 0, stream>>>(
            flag, bufA, h2bf, (int)TD);
        wtrans_kernel<<<dim3(HID_ / 64, DIM_ / 64, 8), 256, 0, stream>>>(
            flag, w1, w1t, DIM_, HID_);
        wtrans_kernel<<<dim3(HID_ / 64, DIM_ / 64, 8), 256, 0, stream>>>(
            flag, w3, w3t, DIM_, HID_);
        wtrans_kernel<<<dim3(HID_ / 64, DIM_ / 64, 1), 256, 0, stream>>>(
            flag, sw1, sw1t, DIM_, HID_);
        wtrans_kernel<<<dim3(HID_ / 64, DIM_ / 64, 1), 256, 0, stream>>>(
            flag, sw3, sw3t, DIM_, HID_);
        moe_h2_kernel<<<dim3(HID_ / 128, 128, 9), 256, 0, stream>>>(
            flag, h2bf, w1t, w3t, sw1t, sw3t, list, counts, offs, he);
        wtrans_kernel<<<dim3(DIM_ / 64, HID_ / 64, 8), 256, 0, stream>>>(
            flag, w2, w2t, HID_, DIM_);
        wtrans_kernel<<<dim3(DIM_ / 64, HID_ / 64, 1), 256, 0, stream>>>(
            flag, sw2, sw2t, HID_, DIM_);
        moe_y2_kernel<<<dim3(DIM_ / 128, 128, 9), 256, 0, stream>>>(
            flag, he, w2t, sw2t, list, counts, offs, egw, (float*)d_out);
    }

    // bf16-external insurance path: per-token MoE with fused residual
    moe_kernel<u16><<<T_, 256, 0, stream>>>(flag, bufA, bufX1f,
                                            (const u16*)d_in[10], (const u16*)d_in[11],
                                            (const u16*)d_in[12], (const u16*)d_in[13],
                                            (const u16*)d_in[14], (const u16*)d_in[15],
                                            eidx, egw, (u16*)d_out);
}

// Round 4
// 1708.662 us; speedup vs baseline: 4.2186x; 1.4820x over previous
//
#include <hip/hip_runtime.h>
#include <hip/hip_bf16.h>

// PK1Block: B=2 S=2048 DIM=2048 NH=16 NKV=4 HD=128 NE=8 TOPK=2 HID=SHID=1024
// External dtype: fp32 (confirmed R4). Pre-gate chain stays fp32-ACCURATE
// (routing flips at ~0.003 logit noise). Attention: split-bf16 MFMA flash.
// MoE: pre-transposed bf16 weights + m97-style MFMA GEMMs (R7).
// R8: projection GEMMs (wq/wk/wv fused, wo) moved to split-bf16 (hi/lo)
// 3-product MFMA -- ~1e-5 rel err, same scheme attention already validated
// end-to-end against the routing gate. Was: fp32 SIMD GEMM, 434us x2 at
// 79 TF vs 157 TF ceiling, occupancy-capped (512-block grid).
#define B_    2
#define S_    2048
#define DIM_  2048
#define NH_   16
#define NKV_  4
#define HD_   128
#define NE_   8
#define HID_  1024
#define T_    (B_*S_)          // 4096 tokens

typedef unsigned short u16;
typedef unsigned int   u32;

#define DT_BF16 1
#define DT_F32  2

template<typename T> struct dtid;
template<> struct dtid<float> { static constexpr int v = DT_F32;  };
template<> struct dtid<u16>   { static constexpr int v = DT_BF16; };

typedef __attribute__((ext_vector_type(8))) short short8;   // 8 x bf16
typedef __attribute__((ext_vector_type(4))) float f32x4;
typedef __attribute__((ext_vector_type(4))) u32   u32x4;

__device__ __forceinline__ float u2f(u16 u) {
    union { u32 i; float f; } v; v.i = ((u32)u) << 16; return v.f;
}
__device__ __forceinline__ u16 f2bf(float f) {
    union { float f; u32 i; } v; v.f = f;
    u32 x = v.i;
    return (u16)((x + 0x7fffu + ((x >> 16) & 1u)) >> 16);   // RNE
}
__device__ __forceinline__ u32 pack2(float lo, float hi) {
    return (u32)f2bf(lo) | ((u32)f2bf(hi) << 16);
}

template<typename T> __device__ __forceinline__ float ldf(const T* p);
template<> __device__ __forceinline__ float ldf<float>(const float* p) { return *p; }
template<> __device__ __forceinline__ float ldf<u16>(const u16* p)     { return u2f(*p); }

template<typename T> __device__ __forceinline__ void stf(T* p, float v);
template<> __device__ __forceinline__ void stf<float>(float* p, float v) { *p = v; }
template<> __device__ __forceinline__ void stf<u16>(u16* p, float v)     { *p = f2bf(v); }

template<typename T> __device__ __forceinline__ float4 ld4(const T* p);
template<> __device__ __forceinline__ float4 ld4<float>(const float* p) {
    return *(const float4*)p;
}
template<> __device__ __forceinline__ float4 ld4<u16>(const u16* p) {
    ushort4 q = *(const ushort4*)p;
    return make_float4(u2f(q.x), u2f(q.y), u2f(q.z), u2f(q.w));
}

// async global->LDS, 16B per lane, linear dest (wave base + lane*16)
#define STG(g, l) __builtin_amdgcn_global_load_lds( \
    (const __attribute__((address_space(1))) unsigned int*)(const void*)(g), \
    (__attribute__((address_space(3))) unsigned int*)(void*)(l), 16, 0, 0)

// ---------------------------------------------------------------- dtype detect
__global__ void detect_kernel(const u32* __restrict__ fcos_words,
                              int* __restrict__ flag)
{
    *flag = (fcos_words[0] == 0x3F800000u) ? DT_F32 : DT_BF16;
}

__global__ void init_kernel(int* __restrict__ counts)   // counts[16]+cursor[16]
{
    if (threadIdx.x < 32) counts[threadIdx.x] = 0;
}

// ------------------------------------------------- RMSNorm: IT in -> fp32 out
template<typename IT, typename WT>
__global__ __launch_bounds__(256) void rmsnorm_kernel(const int* __restrict__ flag,
                                                      const IT* __restrict__ xin,
                                                      const WT* __restrict__ w,
                                                      float* __restrict__ out)
{
    if (*flag != dtid<WT>::v) return;
    int t = blockIdx.x;
    const IT* xb = xin + (size_t)t * DIM_;
    float ss = 0.f;
    for (int d = threadIdx.x; d < DIM_; d += 256) {
        float v = ldf(xb + d);
        ss += v * v;
    }
    #pragma unroll
    for (int o = 32; o > 0; o >>= 1) ss += __shfl_xor(ss, o);
    __shared__ float red[4];
    if ((threadIdx.x & 63) == 0) red[threadIdx.x >> 6] = ss;
    __syncthreads();
    float tot = red[0] + red[1] + red[2] + red[3];
    float inv = rsqrtf(tot * (1.0f / DIM_) + 1e-6f);
    for (int d = threadIdx.x; d < DIM_; d += 256)
        out[(size_t)t * DIM_ + d] = ldf(xb + d) * inv * ldf(w + d);
}

// ---------------------- fp32 GEMM (bf16-external insurance path only)
template<typename T>
__global__ __launch_bounds__(256) void gemm_kernel(const int* __restrict__ flag,
                                                   const float* __restrict__ A,
                                                   const T* __restrict__ Bw,
                                                   float* __restrict__ CF,
                                                   const T* __restrict__ resid,
                                                   int M, int N, int K)
{
    if (*flag != dtid<T>::v) return;
    __shared__ float As[16][132];
    __shared__ float Bs[16][132];
    int t  = threadIdx.x;
    int bm = blockIdx.y, bn = blockIdx.x;

    int ar = t >> 2;
    int ak = (t & 3) << 2;
    int bkr = t >> 4;
    int bc  = (t & 15) << 3;

    const float* Ap0 = A + (size_t)(bm * 128 + ar) * K + ak;
    const float* Ap1 = Ap0 + (size_t)64 * K;
    const T*     Bp  = Bw + (size_t)bkr * N + bn * 128 + bc;

    int lane = t & 63, w = t >> 6;
    int mi = ((lane & 7) + ((w & 1) << 3)) << 3;
    int ni = ((lane >> 3) + ((w >> 1) << 3)) << 3;

    float acc[8][8] = {};

    float4 pa0 = *(const float4*)(Ap0);
    float4 pa1 = *(const float4*)(Ap1);
    float4 pb0 = ld4(Bp);
    float4 pb1 = ld4(Bp + 4);

    for (int k0 = 0; k0 < K; k0 += 16) {
        As[ak + 0][ar]      = pa0.x; As[ak + 1][ar]      = pa0.y;
        As[ak + 2][ar]      = pa0.z; As[ak + 3][ar]      = pa0.w;
        As[ak + 0][ar + 64] = pa1.x; As[ak + 1][ar + 64] = pa1.y;
        As[ak + 2][ar + 64] = pa1.z; As[ak + 3][ar + 64] = pa1.w;
        *(float4*)&Bs[bkr][bc]     = pb0;
        *(float4*)&Bs[bkr][bc + 4] = pb1;
        __syncthreads();

        if (k0 + 16 < K) {
            pa0 = *(const float4*)(Ap0 + k0 + 16);
            pa1 = *(const float4*)(Ap1 + k0 + 16);
            pb0 = ld4(Bp + (size_t)(k0 + 16) * N);
            pb1 = ld4(Bp + (size_t)(k0 + 16) * N + 4);
        }

        #pragma unroll
        for (int kk = 0; kk < 16; ++kk) {
            float4 a0 = *(const float4*)&As[kk][mi];
            float4 a1 = *(const float4*)&As[kk][mi + 4];
            float4 b0 = *(const float4*)&Bs[kk][ni];
            float4 b1 = *(const float4*)&Bs[kk][ni + 4];
            float a[8] = { a0.x, a0.y, a0.z, a0.w, a1.x, a1.y, a1.z, a1.w };
            float b[8] = { b0.x, b0.y, b0.z, b0.w, b1.x, b1.y, b1.z, b1.w };
            #pragma unroll
            for (int i = 0; i < 8; ++i)
                #pragma unroll
                for (int j = 0; j < 8; ++j) acc[i][j] += a[i] * b[j];
        }
        __syncthreads();
    }

    #pragma unroll
    for (int i = 0; i < 8; ++i) {
        size_t off = (size_t)(bm * 128 + mi + i) * N + bn * 128 + ni;
        #pragma unroll
        for (int j = 0; j < 8; ++j) {
            float c = acc[i][j];
            if (resid) c += ldf(resid + off + j);
            CF[off + j] = c;
        }
    }
}

// ---------------- split-bf16 MFMA GEMM: C = A@B^T (+resid), fp32-accurate
// A planes [M][K] bf16 hi/lo, B planes [N][K] bf16 hi/lo. 128x128 tile, BK=32,
// 4 waves (each 64x64), global_load_lds staging, double-buffered. 3 MFMAs per
// product (hi*hi + hi*lo + lo*hi). QKV mode: ok/ov non-null, columns route
// q[0,2048) k[2048,2560) v[2560,3072). wo mode: ok null, resid = x.
__global__ __launch_bounds__(256) void gemm_sp_kernel(const int* __restrict__ flag,
                                                      const u16* __restrict__ Ahi,
                                                      const u16* __restrict__ Alo,
                                                      const u16* __restrict__ Bhi,
                                                      const u16* __restrict__ Blo,
                                                      float* __restrict__ oq,
                                                      float* __restrict__ ok,
                                                      float* __restrict__ ov,
                                                      const float* __restrict__ resid,
                                                      int K)
{
    if (*flag != DT_F32) return;
    int n0 = blockIdx.x * 128, m0 = blockIdx.y * 128;

    float* out; int ncols, col0;
    if (!ok)            { out = oq; col0 = n0;        ncols = (int)gridDim.x * 128; }
    else if (n0 < 2048) { out = oq; col0 = n0;        ncols = 2048; }
    else if (n0 < 2560) { out = ok; col0 = n0 - 2048; ncols = 512; }
    else                { out = ov; col0 = n0 - 2560; ncols = 512; }

    __shared__ __align__(16) u16 LA[2][2][128 * 32];
    __shared__ __align__(16) u16 LB[2][2][128 * 32];

    int t = threadIdx.x;
    int c0 = t, c1 = t + 256;
    int r0 = c0 >> 2, k0 = (c0 & 3) * 8;
    int r1 = c1 >> 2, k1 = (c1 & 3) * 8;

    const u16* a0h = Ahi + (size_t)(m0 + r0) * K + k0;
    const u16* a1h = Ahi + (size_t)(m0 + r1) * K + k1;
    const u16* a0l = Alo + (size_t)(m0 + r0) * K + k0;
    const u16* a1l = Alo + (size_t)(m0 + r1) * K + k1;
    const u16* b0h = Bhi + (size_t)(n0 + r0) * K + k0;
    const u16* b1h = Bhi + (size_t)(n0 + r1) * K + k1;
    const u16* b0l = Blo + (size_t)(n0 + r0) * K + k0;
    const u16* b1l = Blo + (size_t)(n0 + r1) * K + k1;

    #define STAGE_SP(bf, kk) do {                       \
        STG(a0h + (kk), &LA[bf][0][c0 * 8]);            \
        STG(a1h + (kk), &LA[bf][0][c1 * 8]);            \
        STG(a0l + (kk), &LA[bf][1][c0 * 8]);            \
        STG(a1l + (kk), &LA[bf][1][c1 * 8]);            \
        STG(b0h + (kk), &LB[bf][0][c0 * 8]);            \
        STG(b1h + (kk), &LB[bf][0][c1 * 8]);            \
        STG(b0l + (kk), &LB[bf][1][c0 * 8]);            \
        STG(b1l + (kk), &LB[bf][1][c1 * 8]);            \
    } while (0)

    int w = t >> 6, lane = t & 63;
    int q = lane >> 4, l16 = lane & 15;
    int mh = (w & 1) * 64, nh = (w >> 1) * 64;

    f32x4 acc[4][4];
    #pragma unroll
    for (int mt = 0; mt < 4; ++mt)
        #pragma unroll
        for (int nt = 0; nt < 4; ++nt) acc[mt][nt] = (f32x4){0.f, 0.f, 0.f, 0.f};

    const int NK = K / 32;
    STAGE_SP(0, 0);
    asm volatile("s_waitcnt vmcnt(0)" ::: "memory");
    __syncthreads();
    for (int ks = 0; ks < NK; ++ks) {
        int cur = ks & 1;
        if (ks + 1 < NK) {
            if (cur) STAGE_SP(0, (ks + 1) * 32); else STAGE_SP(1, (ks + 1) * 32);
        }
        short8 ah[4], al[4], bh[4], bl[4];
        #pragma unroll
        for (int i = 0; i < 4; ++i) {
            int ra = (mh + i * 16 + l16) * 32 + q * 8;
            ah[i] = *(const short8*)&LA[cur][0][ra];
            al[i] = *(const short8*)&LA[cur][1][ra];
            int rb = (nh + i * 16 + l16) * 32 + q * 8;
            bh[i] = *(const short8*)&LB[cur][0][rb];
            bl[i] = *(const short8*)&LB[cur][1][rb];
        }
        #pragma unroll
        for (int mt = 0; mt < 4; ++mt)
            #pragma unroll
            for (int nt = 0; nt < 4; ++nt) {
                acc[mt][nt] = __builtin_amdgcn_mfma_f32_16x16x32_bf16(ah[mt], bh[nt], acc[mt][nt], 0, 0, 0);
                acc[mt][nt] = __builtin_amdgcn_mfma_f32_16x16x32_bf16(ah[mt], bl[nt], acc[mt][nt], 0, 0, 0);
                acc[mt][nt] = __builtin_amdgcn_mfma_f32_16x16x32_bf16(al[mt], bh[nt], acc[mt][nt], 0, 0, 0);
            }
        asm volatile("s_waitcnt vmcnt(0)" ::: "memory");
        __syncthreads();
    }
    #undef STAGE_SP

    #pragma unroll
    for (int mt = 0; mt < 4; ++mt)
        #pragma unroll
        for (int r = 0; r < 4; ++r) {
            int m = m0 + mh + mt * 16 + q * 4 + r;
            float* orow = out + (size_t)m * ncols + col0 + nh;
            #pragma unroll
            for (int nt = 0; nt < 4; ++nt) {
                float c = acc[mt][nt][r];
                int cc = nt * 16 + l16;
                if (resid) c += resid[(size_t)m * ncols + col0 + nh + cc];
                orow[cc] = c;
            }
        }
}

// ---------------------------------------------------------------- RoPE (fp32, in place)
template<typename FT>
__global__ __launch_bounds__(256) void rope_kernel(const int* __restrict__ flag,
                                                   float* __restrict__ t,
                                                   const FT* __restrict__ fc,
                                                   const FT* __restrict__ fs,
                                                   int nheads, int npairs)
{
    if (*flag != dtid<FT>::v) return;
    int gid = blockIdx.x * 256 + threadIdx.x;
    if (gid >= npairs) return;
    int i    = gid & 63;
    int rest = gid >> 6;
    int h    = rest % nheads;
    int tok  = rest / nheads;
    int spos = tok & (S_ - 1);
    float c = ldf(fc + spos * 64 + i);
    float s = ldf(fs + spos * 64 + i);
    size_t base = ((size_t)tok * nheads + h) * HD_ + 2 * i;
    float t1 = t[base], t2 = t[base + 1];
    t[base]     = t1 * c - t2 * s;
    t[base + 1] = t1 * s + t2 * c;
}

// ---------------------------------------------------------------- fp32 -> bf16 casts
__global__ __launch_bounds__(256) void cast_kernel(const int* __restrict__ flag,
                                                   const float* __restrict__ src,
                                                   u16* __restrict__ dst, int n)
{
    if (*flag != DT_BF16) return;
    int i = blockIdx.x * 256 + threadIdx.x;
    if (i < n) dst[i] = f2bf(src[i]);
}

// h2 fp32 -> bf16 (fp32 mode), 8 elems/thread
__global__ __launch_bounds__(256) void cast_h2_kernel(const int* __restrict__ flag,
                                                      const float* __restrict__ src,
                                                      u16* __restrict__ dst, int n)
{
    if (*flag != DT_F32) return;
    int i = (blockIdx.x * 256 + threadIdx.x) * 8;
    if (i >= n) return;
    float4 a = *(const float4*)&src[i];
    float4 b = *(const float4*)&src[i + 4];
    short8 o;
    o[0] = (short)f2bf(a.x); o[1] = (short)f2bf(a.y);
    o[2] = (short)f2bf(a.z); o[3] = (short)f2bf(a.w);
    o[4] = (short)f2bf(b.x); o[5] = (short)f2bf(b.y);
    o[6] = (short)f2bf(b.z); o[7] = (short)f2bf(b.w);
    *(short8*)&dst[i] = o;
}

// activations fp32 -> bf16 hi + lo planes (fp32 mode), 8 elems/thread
__global__ __launch_bounds__(256) void asplit_kernel(const int* __restrict__ flag,
                                                     const float* __restrict__ src,
                                                     u16* __restrict__ dhi,
                                                     u16* __restrict__ dlo, int n)
{
    if (*flag != DT_F32) return;
    int i = (blockIdx.x * 256 + threadIdx.x) * 8;
    if (i >= n) return;
    float4 a = *(const float4*)&src[i];
    float4 b = *(const float4*)&src[i + 4];
    float xs[8] = { a.x, a.y, a.z, a.w, b.x, b.y, b.z, b.w };
    short8 oh, ol;
    #pragma unroll
    for (int j = 0; j < 8; ++j) {
        u16 h = f2bf(xs[j]);
        oh[j] = (short)h;
        ol[j] = (short)f2bf(xs[j] - u2f(h));
    }
    *(short8*)&dhi[i] = oh;
    *(short8*)&dlo[i] = ol;
}

// ------------------- weight transpose+convert: src fp32 [K][N] -> dst bf16 [N][K]
// tile 64x64, grid (N/64, K/64, experts)
__global__ __launch_bounds__(256) void wtrans_kernel(const int* __restrict__ flag,
                                                     const float* __restrict__ src,
                                                     u16* __restrict__ dst,
                                                     int K, int N)
{
    if (*flag != DT_F32) return;
    size_t zoff = (size_t)blockIdx.z * K * N;
    src += zoff; dst += zoff;
    int n0 = blockIdx.x * 64, k0 = blockIdx.y * 64;
    __shared__ u16 tl[64][72];
    int t  = threadIdx.x;
    int kr = t >> 2;
    int c4 = (t & 3) * 16;
    #pragma unroll
    for (int i = 0; i < 4; ++i) {
        float4 f = *(const float4*)&src[(size_t)(k0 + kr) * N + n0 + c4 + i * 4];
        *(u32*)&tl[kr][c4 + i * 4 + 0] = pack2(f.x, f.y);
        *(u32*)&tl[kr][c4 + i * 4 + 2] = pack2(f.z, f.w);
    }
    __syncthreads();
    int nr = t >> 2;
    int kc = (t & 3) * 16;
    short8 o0, o1;
    #pragma unroll
    for (int i = 0; i < 8; ++i) {
        o0[i] = (short)tl[kc + i][nr];
        o1[i] = (short)tl[kc + 8 + i][nr];
    }
    *(short8*)&dst[(size_t)(n0 + nr) * K + k0 + kc]     = o0;
    *(short8*)&dst[(size_t)(n0 + nr) * K + k0 + kc + 8] = o1;
}

// ----- weight transpose + hi/lo split: src fp32 [K][N] -> dhi/dlo bf16 [N][K]
__global__ __launch_bounds__(256) void wtrans_sp_kernel(const int* __restrict__ flag,
                                                        const float* __restrict__ src,
                                                        u16* __restrict__ dhi,
                                                        u16* __restrict__ dlo,
                                                        int K, int N)
{
    if (*flag != DT_F32) return;
    int n0 = blockIdx.x * 64, k0 = blockIdx.y * 64;
    __shared__ u32 tl[64][68];
    int t  = threadIdx.x;
    int kr = t >> 2;
    int c4 = (t & 3) * 16;
    #pragma unroll
    for (int i = 0; i < 4; ++i) {
        float4 f = *(const float4*)&src[(size_t)(k0 + kr) * N + n0 + c4 + i * 4];
        float xs[4] = { f.x, f.y, f.z, f.w };
        #pragma unroll
        for (int j = 0; j < 4; ++j) {
            u16 h = f2bf(xs[j]);
            u16 l = f2bf(xs[j] - u2f(h));
            tl[kr][c4 + i * 4 + j] = (u32)h | ((u32)l << 16);
        }
    }
    __syncthreads();
    int nr = t >> 2;
    int kc = (t & 3) * 16;
    short8 oh0, ol0, oh1, ol1;
    #pragma unroll
    for (int i = 0; i < 8; ++i) {
        u32 w0 = tl[kc + i][nr];
        u32 w1 = tl[kc + 8 + i][nr];
        oh0[i] = (short)(w0 & 0xffffu); ol0[i] = (short)(w0 >> 16);
        oh1[i] = (short)(w1 & 0xffffu); ol1[i] = (short)(w1 >> 16);
    }
    size_t o = (size_t)(n0 + nr) * K + k0 + kc;
    *(short8*)&dhi[o]     = oh0;
    *(short8*)&dhi[o + 8] = oh1;
    *(short8*)&dlo[o]     = ol0;
    *(short8*)&dlo[o + 8] = ol1;
}

// --------------------------- Flash attention, split-bf16 MFMA (fp32-accurate)
__global__ __launch_bounds__(256) void attn_mfma_kernel(const int* __restrict__ flag,
                                                        int want,
                                                        float* __restrict__ q,
                                                        const float* __restrict__ k,
                                                        const float* __restrict__ v)
{
    if (*flag != want) return;
    int qt = blockIdx.x;          // 0..31 (query tile of 64)
    int h  = blockIdx.y;          // 0..15
    int b  = blockIdx.z;          // 0..1
    int kvh = h >> 2;
    int t = threadIdx.x;
    int wv = t >> 6, lane = t & 63;
    int qf = lane >> 4, l16 = lane & 15;

    __shared__ u16 Khi[32 * 128];         // [j][d] bf16 hi, 256B rows, XOR-swizzled
    __shared__ u16 Klo[32 * 128];
    __shared__ u16 Vthi[128 * 40];        // [d][j] bf16 hi, pitch 40
    __shared__ u16 Vtlo[128 * 40];
    __shared__ u32 Plds[4][16 * 36];      // per-wave P bounce: [q][j] packed hi|lo

    int q0   = qt * 64;
    int qrow = q0 + wv * 16 + l16;        // this lane's query (softmax column)
    const float* kb = k + (size_t)b * S_ * (NKV_ * HD_) + kvh * HD_;
    const float* vb = v + (size_t)b * S_ * (NKV_ * HD_) + kvh * HD_;

    size_t qbase = ((size_t)(b * S_ + qrow) * NH_ + h) * HD_;
    short8 qhi[4], qlo[4];
    #pragma unroll
    for (int c = 0; c < 4; ++c) {
        const float* qp = q + qbase + c * 32 + qf * 8;
        float4 f0 = *(const float4*)qp;
        float4 f1 = *(const float4*)(qp + 4);
        float xs[8] = { f0.x, f0.y, f0.z, f0.w, f1.x, f1.y, f1.z, f1.w };
        #pragma unroll
        for (int u = 0; u < 8; ++u) {
            u16 hh = f2bf(xs[u]);
            qhi[c][u] = (short)hh;
            qlo[c][u] = (short)f2bf(xs[u] - u2f(hh));
        }
    }

    f32x4 Ot[8];                          // O^T[d = dt*16+qf*4+r][q = l16]
    #pragma unroll
    for (int dt = 0; dt < 8; ++dt) Ot[dt] = (f32x4){0.f, 0.f, 0.f, 0.f};
    float m = -1e30f, l = 0.f;
    const float scale = 0.08838834764831845f;

    int sj  = t >> 3;                     // K: row 0..31
    int sa  = t & 7;                      // K: d-group 0..7 (16 floats each)
    int vjp = t & 15;                     // V: j-pair 0..15
    int vdg = t >> 4;                     // V: d-group 0..15 (8 floats each)

    int ntiles = (q0 + 64) >> 5;          // qt*2 + 2
    for (int tile = 0; tile < ntiles; ++tile) {
        int jt0 = tile << 5;
        __syncthreads();
        {
            const float* krow = kb + (size_t)(jt0 + sj) * (NKV_ * HD_);
            #pragma unroll
            for (int i = 0; i < 4; ++i) {
                int d = sa * 16 + i * 4;
                float4 f = *(const float4*)(krow + d);
                ushort4 hi, lo;
                hi.x = f2bf(f.x); lo.x = f2bf(f.x - u2f(hi.x));
                hi.y = f2bf(f.y); lo.y = f2bf(f.y - u2f(hi.y));
                hi.z = f2bf(f.z); lo.z = f2bf(f.z - u2f(hi.z));
                hi.w = f2bf(f.w); lo.w = f2bf(f.w - u2f(hi.w));
                int bix = (d * 2) ^ ((sj & 7) << 4);
                *(ushort4*)&Khi[sj * 128 + (bix >> 1)] = hi;
                *(ushort4*)&Klo[sj * 128 + (bix >> 1)] = lo;
            }
        }
        {
            #pragma unroll
            for (int p = 0; p < 2; ++p) {
                int d = vdg * 8 + p * 4;
                const float* v0 = vb + (size_t)(jt0 + 2 * vjp) * (NKV_ * HD_) + d;
                const float* v1 = v0 + NKV_ * HD_;
                float4 a = *(const float4*)v0;
                float4 c4 = *(const float4*)v1;
                float aa[4] = { a.x, a.y, a.z, a.w };
                float bb[4] = { c4.x, c4.y, c4.z, c4.w };
                #pragma unroll
                for (int i = 0; i < 4; ++i) {
                    int r = d + i;
                    u16 h0 = f2bf(aa[i]); u16 l0 = f2bf(aa[i] - u2f(h0));
                    u16 h1 = f2bf(bb[i]); u16 l1 = f2bf(bb[i] - u2f(h1));
                    *(u32*)&Vthi[r * 40 + vjp * 2] = (u32)h0 | ((u32)h1 << 16);
                    *(u32*)&Vtlo[r * 40 + vjp * 2] = (u32)l0 | ((u32)l1 << 16);
                }
            }
        }
        __syncthreads();

        f32x4 st[2];
        st[0] = (f32x4){0.f, 0.f, 0.f, 0.f};
        st[1] = (f32x4){0.f, 0.f, 0.f, 0.f};
        #pragma unroll
        for (int jt2 = 0; jt2 < 2; ++jt2) {
            int row = jt2 * 16 + l16;
            #pragma unroll
            for (int c = 0; c < 4; ++c) {
                int bix = (c * 64 + qf * 16) ^ ((l16 & 7) << 4);
                short8 khi = *(const short8*)&Khi[row * 128 + (bix >> 1)];
                short8 klo = *(const short8*)&Klo[row * 128 + (bix >> 1)];
                st[jt2] = __builtin_amdgcn_mfma_f32_16x16x32_bf16(khi, qhi[c], st[jt2], 0, 0, 0);
                st[jt2] = __builtin_amdgcn_mfma_f32_16x16x32_bf16(khi, qlo[c], st[jt2], 0, 0, 0);
                st[jt2] = __builtin_amdgcn_mfma_f32_16x16x32_bf16(klo, qhi[c], st[jt2], 0, 0, 0);
            }
        }

        float pv[8];
        float pmax = -1e30f;
        #pragma unroll
        for (int jt2 = 0; jt2 < 2; ++jt2) {
            #pragma unroll
            for (int r = 0; r < 4; ++r) {
                int j = jt0 + jt2 * 16 + qf * 4 + r;
                float s = st[jt2][r] * scale;
                if (j > qrow) s = -1e30f;
                pv[jt2 * 4 + r] = s;
                pmax = fmaxf(pmax, s);
            }
        }
        pmax = fmaxf(pmax, __shfl_xor(pmax, 16));
        pmax = fmaxf(pmax, __shfl_xor(pmax, 32));
        float mn    = fmaxf(m, pmax);
        float alpha = __expf(m - mn);
        m = mn;
        float rs = 0.f;
        u32 pw[8];
        #pragma unroll
        for (int i = 0; i < 8; ++i) {
            float p = __expf(pv[i] - mn);
            rs += p;
            u16 ph = f2bf(p);
            pw[i] = (u32)ph | ((u32)f2bf(p - u2f(ph)) << 16);
        }
        rs += __shfl_xor(rs, 16);
        rs += __shfl_xor(rs, 32);
        l = l * alpha + rs;

        u32* pl = &Plds[wv][l16 * 36];
        *(u32x4*)&pl[qf * 4]      = (u32x4){ pw[0], pw[1], pw[2], pw[3] };
        *(u32x4*)&pl[16 + qf * 4] = (u32x4){ pw[4], pw[5], pw[6], pw[7] };
        asm volatile("s_waitcnt lgkmcnt(0)" ::: "memory");
        __builtin_amdgcn_sched_barrier(0);
        u32x4 w0 = *(const u32x4*)&Plds[wv][l16 * 36 + qf * 8];
        u32x4 w1 = *(const u32x4*)&Plds[wv][l16 * 36 + qf * 8 + 4];
        short8 phi, plo;
        #pragma unroll
        for (int u = 0; u < 4; ++u) {
            phi[u]     = (short)(w0[u] & 0xffffu); plo[u]     = (short)(w0[u] >> 16);
            phi[4 + u] = (short)(w1[u] & 0xffffu); plo[4 + u] = (short)(w1[u] >> 16);
        }

        #pragma unroll
        for (int dt = 0; dt < 8; ++dt) {
            #pragma unroll
            for (int r = 0; r < 4; ++r) Ot[dt][r] *= alpha;
        }
        #pragma unroll
        for (int dt = 0; dt < 8; ++dt) {
            int row = dt * 16 + l16;
            short8 vhi = *(const short8*)&Vthi[row * 40 + qf * 8];
            short8 vlo = *(const short8*)&Vtlo[row * 40 + qf * 8];
            Ot[dt] = __builtin_amdgcn_mfma_f32_16x16x32_bf16(vhi, phi, Ot[dt], 0, 0, 0);
            Ot[dt] = __builtin_amdgcn_mfma_f32_16x16x32_bf16(vhi, plo, Ot[dt], 0, 0, 0);
            Ot[dt] = __builtin_amdgcn_mfma_f32_16x16x32_bf16(vlo, phi, Ot[dt], 0, 0, 0);
        }
    }

    float invl = 1.f / l;
    #pragma unroll
    for (int dt = 0; dt < 8; ++dt) {
        #pragma unroll
        for (int r = 0; r < 4; ++r)
            q[qbase + dt * 16 + qf * 4 + r] = Ot[dt][r] * invl;
    }
}

// ---------------------------------------------------------------- top-2 gate
template<typename T>
__global__ __launch_bounds__(64) void gate_kernel(const int* __restrict__ flag,
                                                  const float* __restrict__ xt,
                                                  const T* __restrict__ gw,
                                                  int* __restrict__ eidx,
                                                  float* __restrict__ egw,
                                                  int* __restrict__ counts)
{
    if (*flag != dtid<T>::v) return;
    int t = blockIdx.x, lane = threadIdx.x;
    float acc[NE_] = {};
    const float* xr = xt + (size_t)t * DIM_;
    for (int d = lane; d < DIM_; d += 64) {
        float xd = xr[d];
        #pragma unroll
        for (int e = 0; e < NE_; ++e) acc[e] += xd * ldf(gw + d * NE_ + e);
    }
    #pragma unroll
    for (int e = 0; e < NE_; ++e)
        #pragma unroll
        for (int off = 32; off > 0; off >>= 1) acc[e] += __shfl_xor(acc[e], off);
    if (lane == 0) {
        int i0 = 0; float m0 = acc[0];
        #pragma unroll
        for (int e = 1; e < NE_; ++e) if (acc[e] > m0) { m0 = acc[e]; i0 = e; }
        int i1 = (i0 == 0) ? 1 : 0; float m1 = acc[i1];
        for (int e = i1 + 1; e < NE_; ++e)
            if (e != i0 && acc[e] > m1) { m1 = acc[e]; i1 = e; }
        float e1  = __expf(m1 - m0);
        float inv = 1.f / (1.f + e1);
        eidx[t * 2] = i0; eidx[t * 2 + 1] = i1;
        egw [t * 2] = inv; egw [t * 2 + 1] = e1 * inv;
        atomicAdd(&counts[i0], 1);
        atomicAdd(&counts[i1], 1);
    }
}

__global__ void offs_kernel(const int* __restrict__ counts, int* __restrict__ offs)
{
    if (threadIdx.x == 0) {
        int off = 0;
        for (int e = 0; e < NE_; ++e) { offs[e] = off; off += counts[e]; }
    }
}

__global__ __launch_bounds__(256) void scatter_kernel(const int* __restrict__ eidx,
                                                      const int* __restrict__ offs,
                                                      int* __restrict__ cursor,
                                                      int* __restrict__ list)
{
    int s = blockIdx.x * 256 + threadIdx.x;
    if (s >= T_ * 2) return;
    int e = eidx[s] & 7;
    int pos = atomicAdd(&cursor[e], 1);
    list[offs[e] + pos] = s;
}

// ------------------- MoE phase A v2: he = silu(X@W1)*(X@W3), bf16 MFMA GEMM
__global__ __launch_bounds__(256) void moe_h2_kernel(const int* __restrict__ flag,
                                                     const u16* __restrict__ h2bf,
                                                     const u16* __restrict__ w1t,
                                                     const u16* __restrict__ w3t,
                                                     const u16* __restrict__ sw1t,
                                                     const u16* __restrict__ sw3t,
                                                     const int* __restrict__ list,
                                                     const int* __restrict__ counts,
                                                     const int* __restrict__ offs,
                                                     u16* __restrict__ he)
{
    if (*flag != DT_F32) return;
    int e   = blockIdx.z;
    int cnt = (e < 8) ? counts[e] : T_;
    int my0 = blockIdx.y * 64;
    if (my0 >= cnt) return;
    int n0   = blockIdx.x * 128;
    int base = ((e < 8) ? offs[e] : 2 * T_) + my0;
    const u16* W1 = (e < 8) ? w1t + (size_t)e * HID_ * DIM_ : sw1t;
    const u16* W3 = (e < 8) ? w3t + (size_t)e * HID_ * DIM_ : sw3t;

    __shared__ __align__(16) u16 Asb[2][64 * 64];       // [m][k] 128B rows
    __shared__ __align__(16) u16 Bsb[2][2][128 * 64];   // [mat][n][k]
    __shared__ int toks[64];

    int t = threadIdx.x;
    if (t < 64) {
        int mm = (my0 + t < cnt) ? my0 + t : cnt - 1;
        toks[t] = (e < 8) ? (list[offs[e] + mm] >> 1) : mm;
    }
    __syncthreads();

    int w = t >> 6, lane = t & 63;
    int q = lane >> 4, l16 = lane & 15;
    int lr = lane >> 3, lc = lane & 7;
    int sx = (lc ^ lr) * 8;              // pre-swizzled source chunk (u16 elems)

    const u16* asrc0 = h2bf + (size_t)toks[w * 16 + lr] * DIM_ + sx;
    const u16* asrc1 = h2bf + (size_t)toks[w * 16 + 8 + lr] * DIM_ + sx;
    const u16* b1s0 = W1 + (size_t)(n0 + w * 32 +  0 + lr) * DIM_ + sx;
    const u16* b1s1 = W1 + (size_t)(n0 + w * 32 +  8 + lr) * DIM_ + sx;
    const u16* b1s2 = W1 + (size_t)(n0 + w * 32 + 16 + lr) * DIM_ + sx;
    const u16* b1s3 = W1 + (size_t)(n0 + w * 32 + 24 + lr) * DIM_ + sx;
    const u16* b3s0 = W3 + (size_t)(n0 + w * 32 +  0 + lr) * DIM_ + sx;
    const u16* b3s1 = W3 + (size_t)(n0 + w * 32 +  8 + lr) * DIM_ + sx;
    const u16* b3s2 = W3 + (size_t)(n0 + w * 32 + 16 + lr) * DIM_ + sx;
    const u16* b3s3 = W3 + (size_t)(n0 + w * 32 + 24 + lr) * DIM_ + sx;

    #define STAGE_H(bf, k0) do {                                        \
        STG(asrc0 + (k0), &Asb[bf][(w * 16) * 64]);                     \
        STG(asrc1 + (k0), &Asb[bf][(w * 16 + 8) * 64]);                 \
        STG(b1s0 + (k0), &Bsb[bf][0][(w * 32) * 64]);                   \
        STG(b1s1 + (k0), &Bsb[bf][0][(w * 32 + 8) * 64]);               \
        STG(b1s2 + (k0), &Bsb[bf][0][(w * 32 + 16) * 64]);              \
        STG(b1s3 + (k0), &Bsb[bf][0][(w * 32 + 24) * 64]);              \
        STG(b3s0 + (k0), &Bsb[bf][1][(w * 32) * 64]);                   \
        STG(b3s1 + (k0), &Bsb[bf][1][(w * 32 + 8) * 64]);               \
        STG(b3s2 + (k0), &Bsb[bf][1][(w * 32 + 16) * 64]);              \
        STG(b3s3 + (k0), &Bsb[bf][1][(w * 32 + 24) * 64]);              \
    } while (0)

    f32x4 acc1[4][2], acc3[4][2];
    #pragma unroll
    for (int mt = 0; mt < 4; ++mt)
        #pragma unroll
        for (int nt = 0; nt < 2; ++nt) {
            acc1[mt][nt] = (f32x4){0.f, 0.f, 0.f, 0.f};
            acc3[mt][nt] = (f32x4){0.f, 0.f, 0.f, 0.f};
        }

    const int NK = DIM_ / 64;            // 32
    STAGE_H(0, 0);
    asm volatile("s_waitcnt vmcnt(0)" ::: "memory");
    __syncthreads();
    for (int ks = 0; ks < NK; ++ks) {
        int cur = ks & 1;
        if (ks + 1 < NK) {
            if (cur) STAGE_H(0, (ks + 1) * 64); else STAGE_H(1, (ks + 1) * 64);
        }
        #pragma unroll
        for (int ksub = 0; ksub < 2; ++ksub) {
            int ch = (((ksub << 2) + q) ^ (l16 & 7)) * 8;
            short8 af[4];
            #pragma unroll
            for (int mt = 0; mt < 4; ++mt)
                af[mt] = *(const short8*)&Asb[cur][(mt * 16 + l16) * 64 + ch];
            #pragma unroll
            for (int nt = 0; nt < 2; ++nt) {
                int boff = (w * 32 + nt * 16 + l16) * 64 + ch;
                short8 b1 = *(const short8*)&Bsb[cur][0][boff];
                short8 b3 = *(const short8*)&Bsb[cur][1][boff];
                #pragma unroll
                for (int mt = 0; mt < 4; ++mt) {
                    acc1[mt][nt] = __builtin_amdgcn_mfma_f32_16x16x32_bf16(af[mt], b1, acc1[mt][nt], 0, 0, 0);
                    acc3[mt][nt] = __builtin_amdgcn_mfma_f32_16x16x32_bf16(af[mt], b3, acc3[mt][nt], 0, 0, 0);
                }
            }
        }
        asm volatile("s_waitcnt vmcnt(0)" ::: "memory");
        __syncthreads();
    }
    #undef STAGE_H

    #pragma unroll
    for (int mt = 0; mt < 4; ++mt)
        #pragma unroll
        for (int nt = 0; nt < 2; ++nt)
            #pragma unroll
            for (int r = 0; r < 4; ++r) {
                int m = mt * 16 + q * 4 + r;
                if (my0 + m < cnt) {
                    float h1 = acc1[mt][nt][r], h3 = acc3[mt][nt][r];
                    float vv = (h1 / (1.f + __expf(-h1))) * h3;
                    he[(size_t)(base + m) * HID_ + n0 + w * 32 + nt * 16 + l16] = f2bf(vv);
                }
            }
}

// ------------------- MoE phase B v2: out += g * (he @ W2), bf16 MFMA + atomics
__global__ __launch_bounds__(256) void moe_y2_kernel(const int* __restrict__ flag,
                                                     const u16* __restrict__ he,
                                                     const u16* __restrict__ w2t,
                                                     const u16* __restrict__ sw2t,
                                                     const int* __restrict__ list,
                                                     const int* __restrict__ counts,
                                                     const int* __restrict__ offs,
                                                     const float* __restrict__ egw,
                                                     float* __restrict__ out)
{
    if (*flag != DT_F32) return;
    int e   = blockIdx.z;
    int cnt = (e < 8) ? counts[e] : T_;
    int my0 = blockIdx.y * 64;
    if (my0 >= cnt) return;
    int d0   = blockIdx.x * 128;
    int base = ((e < 8) ? offs[e] : 2 * T_) + my0;
    const u16* W2 = (e < 8) ? w2t + (size_t)e * DIM_ * HID_ : sw2t;

    __shared__ __align__(16) u16 Asb[2][64 * 64];
    __shared__ __align__(16) u16 Bsb[2][128 * 64];
    __shared__ int   stok[64];
    __shared__ float sg[64];

    int t = threadIdx.x;
    if (t < 64) {
        int mm = (my0 + t < cnt) ? my0 + t : cnt - 1;
        if (e < 8) {
            int s = list[offs[e] + mm];
            stok[t] = s >> 1; sg[t] = egw[s];
        } else {
            stok[t] = mm; sg[t] = 1.f;
        }
    }
    __syncthreads();

    int w = t >> 6, lane = t & 63;
    int q = lane >> 4, l16 = lane & 15;
    int lr = lane >> 3, lc = lane & 7;
    int sx = (lc ^ lr) * 8;

    const u16* asrc0 = he + (size_t)(base + w * 16 + lr) * HID_ + sx;
    const u16* asrc1 = he + (size_t)(base + w * 16 + 8 + lr) * HID_ + sx;
    const u16* bs0 = W2 + (size_t)(d0 + w * 32 +  0 + lr) * HID_ + sx;
    const u16* bs1 = W2 + (size_t)(d0 + w * 32 +  8 + lr) * HID_ + sx;
    const u16* bs2 = W2 + (size_t)(d0 + w * 32 + 16 + lr) * HID_ + sx;
    const u16* bs3 = W2 + (size_t)(d0 + w * 32 + 24 + lr) * HID_ + sx;

    #define STAGE_Y(bf, k0) do {                                        \
        STG(asrc0 + (k0), &Asb[bf][(w * 16) * 64]);                     \
        STG(asrc1 + (k0), &Asb[bf][(w * 16 + 8) * 64]);                 \
        STG(bs0 + (k0), &Bsb[bf][(w * 32) * 64]);                       \
        STG(bs1 + (k0), &Bsb[bf][(w * 32 + 8) * 64]);                   \
        STG(bs2 + (k0), &Bsb[bf][(w * 32 + 16) * 64]);                  \
        STG(bs3 + (k0), &Bsb[bf][(w * 32 + 24) * 64]);                  \
    } while (0)

    f32x4 acc[4][2];
    #pragma unroll
    for (int mt = 0; mt < 4; ++mt)
        #pragma unroll
        for (int nt = 0; nt < 2; ++nt) acc[mt][nt] = (f32x4){0.f, 0.f, 0.f, 0.f};

    const int NK = HID_ / 64;            // 16
    STAGE_Y(0, 0);
    asm volatile("s_waitcnt vmcnt(0)" ::: "memory");
    __syncthreads();
    for (int ks = 0; ks < NK; ++ks) {
        int cur = ks & 1;
        if (ks + 1 < NK) {
            if (cur) STAGE_Y(0, (ks + 1) * 64); else STAGE_Y(1, (ks + 1) * 64);
        }
        #pragma unroll
        for (int ksub = 0; ksub < 2; ++ksub) {
            int ch = (((ksub << 2) + q) ^ (l16 & 7)) * 8;
            short8 af[4];
            #pragma unroll
            for (int mt = 0; mt < 4; ++mt)
                af[mt] = *(const short8*)&Asb[cur][(mt * 16 + l16) * 64 + ch];
            #pragma unroll
            for (int nt = 0; nt < 2; ++nt) {
                short8 bf_ = *(const short8*)&Bsb[cur][(w * 32 + nt * 16 + l16) * 64 + ch];
                #pragma unroll
                for (int mt = 0; mt < 4; ++mt)
                    acc[mt][nt] = __builtin_amdgcn_mfma_f32_16x16x32_bf16(af[mt], bf_, acc[mt][nt], 0, 0, 0);
            }
        }
        asm volatile("s_waitcnt vmcnt(0)" ::: "memory");
        __syncthreads();
    }
    #undef STAGE_Y

    #pragma unroll
    for (int mt = 0; mt < 4; ++mt)
        #pragma unroll
        for (int r = 0; r < 4; ++r) {
            int m = mt * 16 + q * 4 + r;
            if (my0 + m < cnt) {
                int   tok = stok[m];
                float g   = sg[m];
                float* orow = out + (size_t)tok * DIM_ + d0 + w * 32 + l16;
                unsafeAtomicAdd(orow,      g * acc[mt][0][r]);
                unsafeAtomicAdd(orow + 16, g * acc[mt][1][r]);
            }
        }
}

// --------------- old per-token MoE: bf16-external insurance path only
template<typename T>
__global__ __launch_bounds__(256) void moe_kernel(const int* __restrict__ flag,
                                                  const float* __restrict__ h2,
                                                  const float* __restrict__ x1,
                                                  const T* __restrict__ w1,
                                                  const T* __restrict__ w2,
                                                  const T* __restrict__ w3,
                                                  const T* __restrict__ sw1,
                                                  const T* __restrict__ sw2,
                                                  const T* __restrict__ sw3,
                                                  const int* __restrict__ eidx,
                                                  const float* __restrict__ egw,
                                                  T* __restrict__ out)
{
    if (*flag != dtid<T>::v) return;
    int t = blockIdx.x;
    int j = threadIdx.x;
    __shared__ float sx[DIM_];
    __shared__ float she[HID_];
    for (int d = j; d < DIM_; d += 256)
        sx[d] = h2[(size_t)t * DIM_ + d];
    __syncthreads();

    float y[8] = {};
    for (int pass = 0; pass < 3; ++pass) {
        const T *W1, *W2, *W3; float g;
        if (pass < 2) {
            int e = eidx[t * 2 + pass] & 7;
            g = egw[t * 2 + pass];
            W1 = w1 + (size_t)e * DIM_ * HID_;
            W3 = w3 + (size_t)e * DIM_ * HID_;
            W2 = w2 + (size_t)e * HID_ * DIM_;
        } else {
            W1 = sw1; W3 = sw3; W2 = sw2; g = 1.f;
        }
        float a1[4] = {}, a3[4] = {};
        for (int d = 0; d < DIM_; ++d) {
            float xd = sx[d];
            const T* r1 = W1 + (size_t)d * HID_;
            const T* r3 = W3 + (size_t)d * HID_;
            #pragma unroll
            for (int i = 0; i < 4; ++i) {
                a1[i] += xd * ldf(r1 + j + 256 * i);
                a3[i] += xd * ldf(r3 + j + 256 * i);
            }
        }
        #pragma unroll
        for (int i = 0; i < 4; ++i) {
            float h1 = a1[i];
            she[j + 256 * i] = g * (h1 / (1.f + __expf(-h1))) * a3[i];
        }
        __syncthreads();
        for (int hh = 0; hh < HID_; ++hh) {
            float hv = she[hh];
            const T* r2 = W2 + (size_t)hh * DIM_;
            #pragma unroll
            for (int i = 0; i < 8; ++i) y[i] += hv * ldf(r2 + j + 256 * i);
        }
        __syncthreads();
    }
    #pragma unroll
    for (int i = 0; i < 8; ++i) {
        size_t idx = (size_t)t * DIM_ + j + 256 * i;
        stf(out + idx, y[i] + x1[idx]);
    }
}

// ================================================================ launch
extern "C" void kernel_launch(void* const* d_in, const int* in_sizes, int n_in,
                              void* d_out, int out_size, void* d_ws, size_t ws_size,
                              hipStream_t stream)
{
    const size_t TD  = (size_t)T_ * DIM_;            // 8.4M elems
    const size_t TKV = (size_t)T_ * NKV_ * HD_;      // 2.1M elems

    char* ws = (char*)d_ws;
    int*   flag   = (int*)ws;   ws += 16;
    int*   counts = (int*)ws;   ws += 16 * 4;        // counts[16]
    int*   cursor = counts + 16;
    ws += 16 * 4;                                    // cursor[16]
    int*   offs   = (int*)ws;   ws += 16 * 4;
    int*   eidx   = (int*)ws;   ws += (size_t)T_ * 2 * 4;
    float* egw    = (float*)ws; ws += (size_t)T_ * 2 * 4;
    int*   list   = (int*)ws;   ws += (size_t)T_ * 2 * 4;
    float* bufA   = (float*)ws; ws += TD * 4;        // h / A2-planes / h2 / w1t,w2t
    float* bufB   = (float*)ws; ws += TD * 4;        // q,attn-out; he + sw1t/sw3t
    u16*   he     = (u16*)bufB;                      // 12288*1024 bf16 = 25.2MB
    float* bufKV  = (float*)ws; ws += 2 * TKV * 4;   // bf16-mode KV; fp32: h2bf/sw2t
    float* bufX1f = (float*)ws; ws += TD * 4;        // bf16-mode x1; fp32: W-planes, w3t

    detect_kernel<<<1, 1, 0, stream>>>((const u32*)d_in[1], flag);
    init_kernel<<<1, 64, 0, stream>>>(counts);

    dim3 gattn(S_ / 64, NH_, B_);
    int qpairs = T_ * NH_ * (HD_ / 2);
    int kpairs = T_ * NKV_ * (HD_ / 2);

    // ======================= fp32 main path =======================
    {
        const float* x      = (const float*)d_in[0];
        const float* fcos   = (const float*)d_in[1];
        const float* fsin   = (const float*)d_in[2];
        const float* attn_w = (const float*)d_in[3];
        const float* ffn_w  = (const float*)d_in[4];
        const float* wq     = (const float*)d_in[5];
        const float* wk     = (const float*)d_in[6];
        const float* wv     = (const float*)d_in[7];
        const float* wo     = (const float*)d_in[8];
        const float* gate_w = (const float*)d_in[9];
        float* out_x = (float*)d_out;
        float* kf    = out_x + TD;
        float* vf    = kf + TKV;

        // scratch: A-planes in the not-yet-written d_out x region (exact fit)
        u16* Ahi = (u16*)out_x;
        u16* Alo = Ahi + TD;
        // W-planes in bufX1f: qkv fused [3072][2048] hi+lo = 25.2MB <= 33.5MB
        u16* Whi = (u16*)bufX1f;
        u16* Wlo = Whi + (size_t)3072 * DIM_;

        rmsnorm_kernel<float, float><<<T_, 256, 0, stream>>>(flag, x, attn_w, bufA);
        asplit_kernel<<<(int)(TD / (256 * 8)), 256, 0, stream>>>(flag, bufA, Ahi, Alo, (int)TD);
        wtrans_sp_kernel<<<dim3(2048 / 64, DIM_ / 64), 256, 0, stream>>>(
            flag, wq, Whi, Wlo, DIM_, 2048);
        wtrans_sp_kernel<<<dim3(512 / 64, DIM_ / 64), 256, 0, stream>>>(
            flag, wk, Whi + (size_t)2048 * DIM_, Wlo + (size_t)2048 * DIM_, DIM_, 512);
        wtrans_sp_kernel<<<dim3(512 / 64, DIM_ / 64), 256, 0, stream>>>(
            flag, wv, Whi + (size_t)2560 * DIM_, Wlo + (size_t)2560 * DIM_, DIM_, 512);
        // fused QKV: grid (3072/128, 4096/128)
        gemm_sp_kernel<<<dim3(24, 32), 256, 0, stream>>>(
            flag, Ahi, Alo, Whi, Wlo, bufB, kf, vf, nullptr, DIM_);
        rope_kernel<float><<<(qpairs + 255) / 256, 256, 0, stream>>>(
            flag, bufB, fcos, fsin, NH_, qpairs);
        rope_kernel<float><<<(kpairs + 255) / 256, 256, 0, stream>>>(
            flag, kf, fcos, fsin, NKV_, kpairs);
        attn_mfma_kernel<<<gattn, 256, 0, stream>>>(flag, DT_F32, bufB, kf, vf);
        // wo: W-planes overwrite qkv planes (dead); A2-planes in bufA (h dead)
        wtrans_sp_kernel<<<dim3(2048 / 64, DIM_ / 64), 256, 0, stream>>>(
            flag, wo, Whi, Wlo, DIM_, 2048);
        u16* A2hi = (u16*)bufA;
        u16* A2lo = A2hi + TD;
        asplit_kernel<<<(int)(TD / (256 * 8)), 256, 0, stream>>>(flag, bufB, A2hi, A2lo, (int)TD);
        gemm_sp_kernel<<<dim3(16, 32), 256, 0, stream>>>(
            flag, A2hi, A2lo, Whi, Wlo, out_x, nullptr, nullptr, x, DIM_);
        rmsnorm_kernel<float, float><<<T_, 256, 0, stream>>>(flag, out_x, ffn_w, bufA);
        gate_kernel<float><<<T_, 64, 0, stream>>>(flag, bufA, gate_w, eidx, egw, counts);
    }

    // ======================= bf16 insurance path =======================
    {
        typedef u16 T;
        const T* x      = (const T*)d_in[0];
        const T* fcos   = (const T*)d_in[1];
        const T* fsin   = (const T*)d_in[2];
        const T* attn_w = (const T*)d_in[3];
        const T* ffn_w  = (const T*)d_in[4];
        const T* wq     = (const T*)d_in[5];
        const T* wk     = (const T*)d_in[6];
        const T* wv     = (const T*)d_in[7];
        const T* wo     = (const T*)d_in[8];
        const T* gate_w = (const T*)d_in[9];
        T* out_x = (T*)d_out;
        T* out_k = out_x + TD;
        T* out_v = out_k + TKV;
        float* kf  = bufKV;
        float* vf  = bufKV + TKV;
        float* x1f = bufX1f;
        dim3 gq(DIM_ / 128, T_ / 128);
        dim3 gkv((NKV_ * HD_) / 128, T_ / 128);
        rmsnorm_kernel<T, T><<<T_, 256, 0, stream>>>(flag, x, attn_w, bufA);
        gemm_kernel<T><<<gq,  256, 0, stream>>>(flag, bufA, wq, bufB,
                                                (const T*)nullptr, T_, DIM_, DIM_);
        gemm_kernel<T><<<gkv, 256, 0, stream>>>(flag, bufA, wk, kf,
                                                (const T*)nullptr, T_, NKV_ * HD_, DIM_);
        gemm_kernel<T><<<gkv, 256, 0, stream>>>(flag, bufA, wv, vf,
                                                (const T*)nullptr, T_, NKV_ * HD_, DIM_);
        rope_kernel<T><<<(qpairs + 255) / 256, 256, 0, stream>>>(
            flag, bufB, fcos, fsin, NH_, qpairs);
        rope_kernel<T><<<(kpairs + 255) / 256, 256, 0, stream>>>(
            flag, kf, fcos, fsin, NKV_, kpairs);
        cast_kernel<<<(int)((TKV + 255) / 256), 256, 0, stream>>>(
            flag, kf, (u16*)out_k, (int)TKV);
        cast_kernel<<<(int)((TKV + 255) / 256), 256, 0, stream>>>(
            flag, vf, (u16*)out_v, (int)TKV);
        attn_mfma_kernel<<<gattn, 256, 0, stream>>>(flag, DT_BF16, bufB, kf, vf);
        gemm_kernel<T><<<gq, 256, 0, stream>>>(flag, bufB, wo, x1f, x,
                                               T_, DIM_, DIM_);
        rmsnorm_kernel<float, T><<<T_, 256, 0, stream>>>(flag, x1f, ffn_w, bufA);
        gate_kernel<T><<<T_, 64, 0, stream>>>(flag, bufA, gate_w, eidx, egw, counts);
    }

    offs_kernel<<<1, 1, 0, stream>>>(counts, offs);
    scatter_kernel<<<(T_ * 2 + 255) / 256, 256, 0, stream>>>(eidx, offs, cursor, list);

    // fp32 path: pre-transpose weights to bf16 [n][k], then MFMA MoE
    {
        const float* w1  = (const float*)d_in[10];
        const float* w2  = (const float*)d_in[11];
        const float* w3  = (const float*)d_in[12];
        const float* sw1 = (const float*)d_in[13];
        const float* sw2 = (const float*)d_in[14];
        const float* sw3 = (const float*)d_in[15];

        u16* w1t  = (u16*)bufA;                       // 32MB (h2 dead after cast)
        u16* w3t  = (u16*)bufX1f;                     // 32MB (W-planes dead)
        u16* h2bf = (u16*)bufKV;                      // 16.8MB
        u16* sw1t = (u16*)((char*)bufB + (size_t)(3 * T_) * HID_ * 2);  // he end
        u16* sw3t = sw1t + (size_t)HID_ * DIM_;
        u16* w2t  = (u16*)bufA;                       // reuse after moe_h2
        u16* sw2t = (u16*)bufKV;                      // reuse after moe_h2

        cast_h2_kernel<<<(int)(TD / (256 * 8)), 256, 0, stream>>>(
            flag, bufA, h2bf, (int)TD);
        wtrans_kernel<<<dim3(HID_ / 64, DIM_ / 64, 8), 256, 0, stream>>>(
            flag, w1, w1t, DIM_, HID_);
        wtrans_kernel<<<dim3(HID_ / 64, DIM_ / 64, 8), 256, 0, stream>>>(
            flag, w3, w3t, DIM_, HID_);
        wtrans_kernel<<<dim3(HID_ / 64, DIM_ / 64, 1), 256, 0, stream>>>(
            flag, sw1, sw1t, DIM_, HID_);
        wtrans_kernel<<<dim3(HID_ / 64, DIM_ / 64, 1), 256, 0, stream>>>(
            flag, sw3, sw3t, DIM_, HID_);
        moe_h2_kernel<<<dim3(HID_ / 128, 128, 9), 256, 0, stream>>>(
            flag, h2bf, w1t, w3t, sw1t, sw3t, list, counts, offs, he);
        wtrans_kernel<<<dim3(DIM_ / 64, HID_ / 64, 8), 256, 0, stream>>>(
            flag, w2, w2t, HID_, DIM_);
        wtrans_kernel<<<dim3(DIM_ / 64, HID_ / 64, 1), 256, 0, stream>>>(
            flag, sw2, sw2t, HID_, DIM_);
        moe_y2_kernel<<<dim3(DIM_ / 128, 128, 9), 256, 0, stream>>>(
            flag, he, w2t, sw2t, list, counts, offs, egw, (float*)d_out);
    }

    // bf16-external insurance path: per-token MoE with fused residual
    moe_kernel<u16><<<T_, 256, 0, stream>>>(flag, bufA, bufX1f,
                                            (const u16*)d_in[10], (const u16*)d_in[11],
                                            (const u16*)d_in[12], (const u16*)d_in[13],
                                            (const u16*)d_in[14], (const u16*)d_in[15],
                                            eidx, egw, (u16*)d_out);
}